// Round 18
// baseline (498.700 us; speedup 1.0000x reference)
//
#include <hip/hip_runtime.h>
#include <cstddef>

typedef __attribute__((ext_vector_type(8))) short bf16x8;
typedef __attribute__((ext_vector_type(8), aligned(8))) short bf16x8a;
typedef __attribute__((ext_vector_type(4))) float f32x4;
typedef __attribute__((ext_vector_type(4))) unsigned short u16x4;
typedef __attribute__((ext_vector_type(8))) unsigned short u16x8;

__device__ inline unsigned short f2bf(float f) {
  unsigned int u = __float_as_uint(f);
  unsigned int r = (u + 0x7FFFu + ((u >> 16) & 1u)) >> 16;
  return (unsigned short)r;
}
__device__ inline float bf2f(unsigned short u) {
  return __uint_as_float((unsigned int)u << 16);
}

// ---------------- prep: x (32,3,152,152) f32 -> xb1 bf16 [ih152][iw160][b32][ic4]
__global__ __launch_bounds__(256) void prep_xb1(const float* __restrict__ x,
                                                unsigned short* __restrict__ xb) {
  const int j = blockIdx.x * 256 + threadIdx.x;   // 32*152*160 = 778240 exact
  const int iw = j % 160;
  const int ih = (j / 160) % 152;
  const int b = j / (160 * 152);
  unsigned short v[4] = {0, 0, 0, 0};
  if (iw < 152) {
    #pragma unroll
    for (int ic = 0; ic < 3; ++ic)
      v[ic] = f2bf(x[(size_t)(b * 3 + ic) * 23104 + ih * 152 + iw]);
  }
  *(unsigned long long*)(xb + ((((size_t)ih * 160 + iw) * 32) + b) * 4) =
      *(unsigned long long*)v;
}

// ---------------- prep: conv1 w (32,3,11,11) -> A-table wb1 [step17][kc4][s32][8]
__global__ __launch_bounds__(256) void prep_wb1(const float* __restrict__ w,
                                                unsigned short* __restrict__ wb) {
  const int j = blockIdx.x * 256 + threadIdx.x;   // 17408 exact
  const int e = j & 7;
  const int s = (j >> 3) & 31;
  const int kcj = j >> 8;
  const int kc = kcj & 3, step = kcj >> 2;
  const int t = step * 8 + kc * 2 + (e >> 2);
  const int ics = e & 3;
  const int kh = t / 12, kwp = t - kh * 12;
  float val = 0.f;
  if (t < 132 && kwp < 11 && ics < 3)
    val = w[((s * 3 + ics) * 11 + kh) * 11 + kwp];
  wb[j] = f2bf(val);
}

// ---------------- conv1 via MFMA: writes c1B bf16 [pos20164][b32][oc32].
__global__ __launch_bounds__(256, 4) void conv1_mfma(const unsigned short* __restrict__ xb,
                                                     const unsigned short* __restrict__ wb,
                                                     const float* __restrict__ bias,
                                                     unsigned short* __restrict__ outB) {
  const int lane = threadIdx.x & 63;
  const int wvi = threadIdx.x >> 6;
  const int pos = blockIdx.x * 4 + wvi;           // 5041*4 = 20164 exact
  const int oh = pos / 142, ow = pos % 142;
  const int row = lane & 15;
  const int kc = lane >> 4;
  f32x4 a00 = {0.f, 0.f, 0.f, 0.f}, a01 = a00, a10 = a00, a11 = a00;

  #pragma unroll 2
  for (int j = 0; j < 17; ++j) {
    const int t0 = j * 8 + 2 * kc;
    int kh = t0 / 12;
    int kwp = t0 - kh * 12;
    if (t0 >= 132) { kh = 0; kwp = 0; }
    const bf16x8 wa0 = *(const bf16x8*)(wb + (((j * 4 + kc) * 32) + row) * 8);
    const bf16x8 wa1 = *(const bf16x8*)(wb + (((j * 4 + kc) * 32) + 16 + row) * 8);
    const size_t base = (((size_t)(oh + kh) * 160) + (ow + kwp)) * 128;
    const unsigned short* xp0 = xb + base + row * 4;
    bf16x8 xv0, xv1;
    ((unsigned long long*)&xv0)[0] = *(const unsigned long long*)(xp0);
    ((unsigned long long*)&xv0)[1] = *(const unsigned long long*)(xp0 + 128);
    ((unsigned long long*)&xv1)[0] = *(const unsigned long long*)(xp0 + 64);
    ((unsigned long long*)&xv1)[1] = *(const unsigned long long*)(xp0 + 192);
    a00 = __builtin_amdgcn_mfma_f32_16x16x32_bf16(wa0, xv0, a00, 0, 0, 0);
    a01 = __builtin_amdgcn_mfma_f32_16x16x32_bf16(wa0, xv1, a01, 0, 0, 0);
    a10 = __builtin_amdgcn_mfma_f32_16x16x32_bf16(wa1, xv0, a10, 0, 0, 0);
    a11 = __builtin_amdgcn_mfma_f32_16x16x32_bf16(wa1, xv1, a11, 0, 0, 0);
  }

  unsigned short* ob = outB + (size_t)pos * 1024;
  u16x4 p00, p01, p10, p11;
  #pragma unroll
  for (int r = 0; r < 4; ++r) {
    const float bv0 = bias[kc * 4 + r];
    const float bv1 = bias[16 + kc * 4 + r];
    p00[r] = f2bf(fmaxf(a00[r] + bv0, 0.f));
    p01[r] = f2bf(fmaxf(a01[r] + bv0, 0.f));
    p10[r] = f2bf(fmaxf(a10[r] + bv1, 0.f));
    p11[r] = f2bf(fmaxf(a11[r] + bv1, 0.f));
  }
  *(u16x4*)(ob + row * 32 + kc * 4) = p00;
  *(u16x4*)(ob + (row + 16) * 32 + kc * 4) = p01;
  *(u16x4*)(ob + row * 32 + 16 + kc * 4) = p10;
  *(u16x4*)(ob + (row + 16) * 32 + 16 + kc * 4) = p11;
}

// ---------------- pool_t2: maxpool(3,2,1) on c1B [pos][b32][oc32] -> xb2
// [pos'5041][b32][ic32]. Integer max valid (relu >= 0).
__global__ __launch_bounds__(256) void pool_t2(const unsigned short* __restrict__ in,
                                               unsigned short* __restrict__ xb) {
  const int tid = threadIdx.x;
  const int b = tid & 31, pg = tid >> 5;
  const int posp = blockIdx.x * 8 + pg;
  if (posp >= 5041) return;
  const int ohp = posp / 71, owp = posp % 71;
  u16x8 m[4];
  #pragma unroll
  for (int q = 0; q < 4; ++q)
    #pragma unroll
    for (int e = 0; e < 8; ++e) m[q][e] = 0;

  #pragma unroll
  for (int kh = 0; kh < 3; ++kh) {
    const int ih = ohp * 2 - 1 + kh;
    if (ih < 0 || ih >= 142) continue;
    #pragma unroll
    for (int kw = 0; kw < 3; ++kw) {
      const int iw = owp * 2 - 1 + kw;
      if (iw < 0 || iw >= 142) continue;
      const u16x8* p =
          (const u16x8*)(in + (((size_t)(ih * 142 + iw)) * 32 + b) * 32);
      #pragma unroll
      for (int q = 0; q < 4; ++q) {
        const u16x8 v = p[q];
        #pragma unroll
        for (int e = 0; e < 8; ++e) m[q][e] = (v[e] > m[q][e]) ? v[e] : m[q][e];
      }
    }
  }
  u16x8* o = (u16x8*)(xb + ((size_t)posp * 32 + b) * 32);
  #pragma unroll
  for (int q = 0; q < 4; ++q) o[q] = m[q];
}

// ---------------- wb2: conv2 w (16,32,9,9) -> [sp81][oc16][ic32] bf16
__global__ __launch_bounds__(256) void prep_wb2(const float* __restrict__ w,
                                                unsigned short* __restrict__ wb) {
  const int j = blockIdx.x * 256 + threadIdx.x;
  if (j >= 81 * 16 * 32) return;
  const int ic = j & 31, oc = (j >> 5) & 15, sp = j >> 9;
  wb[j] = f2bf(w[(size_t)oc * 2592 + ic * 81 + sp]);
}

// ---------------- conv2 via MFMA, b-split: wave = (pos, b-half); 2x waves.
__global__ __launch_bounds__(256) void conv2_mfma(const unsigned short* __restrict__ xb,
                                                  const unsigned short* __restrict__ wb,
                                                  const float* __restrict__ bias,
                                                  unsigned short* __restrict__ outB) {
  const int lane = threadIdx.x & 63;
  const int wvi = threadIdx.x >> 6;
  int unit = blockIdx.x * 4 + wvi;                // pos*2 + bh
  if (unit > 7937) unit = 7937;
  const int pos = unit >> 1, bh = unit & 1;
  const int oh = pos / 63, ow = pos % 63;
  const int row = lane & 15;                      // b column (within half)
  const int kc = lane >> 4;
  f32x4 acc0 = {0.f, 0.f, 0.f, 0.f};
  const unsigned short* xbase = xb + (size_t)(oh * 71 + ow) * 1024;
  const int aoff = row * 32 + kc * 8;
  const int boff = (row + bh * 16) * 32 + kc * 8;

  #pragma unroll
  for (int kh = 0; kh < 9; ++kh) {
    #pragma unroll
    for (int kw = 0; kw < 9; ++kw) {
      const int sp = kh * 9 + kw;
      const bf16x8 a = *(const bf16x8*)(wb + sp * 512 + aoff);
      const bf16x8 b0 = *(const bf16x8*)(xbase + (kh * 71 + kw) * 1024 + boff);
      acc0 = __builtin_amdgcn_mfma_f32_16x16x32_bf16(a, b0, acc0, 0, 0, 0);
    }
  }

  u16x4 pk0;
  #pragma unroll
  for (int r = 0; r < 4; ++r) {
    const float bv = bias[kc * 4 + r];
    pk0[r] = f2bf(fmaxf(acc0[r] + bv, 0.f));
  }
  *(u16x4*)(outB + (size_t)pos * 512 + (row + bh * 16) * 16 + kc * 4) = pk0;
}

// ---------------- lc weight prep: w [pos][oc16][ic16][KHW] f32 ->
// wbT bf16 [lpos][pair][oc16][tl2*ic16]; LDS-staged, coalesced read+write.
template <int KH>
__global__ __launch_bounds__(256) void prep_lcw(const float* __restrict__ w,
                                                unsigned short* __restrict__ wbT,
                                                int pos_base) {
  constexpr int KHW = KH * KH;
  constexpr int P = (KHW + 1) / 2;
  __shared__ float ls[8 * 16 * KHW];
  const int tid = threadIdx.x;
  const float* wp = w + (size_t)(pos_base + blockIdx.x) * (256 * KHW);
  unsigned short* ob = wbT + (size_t)blockIdx.x * (P * 512);

  for (int half = 0; half < 2; ++half) {
    __syncthreads();
    for (int j = tid; j < 8 * 16 * KHW; j += 256)
      ls[j] = wp[half * (8 * 16 * KHW) + j];
    __syncthreads();
    for (int j = tid; j < P * 256; j += 256) {
      const int ic = j & 15, tl = (j >> 4) & 1, oc8 = (j >> 5) & 7, pair = j >> 8;
      const int tap = pair * 2 + tl;
      const float v = (tap < KHW) ? ls[(oc8 * 16 + ic) * KHW + tap] : 0.f;
      ob[(size_t)pair * 512 + (half * 8 + oc8) * 32 + tl * 16 + ic] = f2bf(v);
    }
  }
}

// ---------------- lc via MFMA, b-split: wave = (pos, b-half); 2x waves.
template <int KH, int S, int IH, int OH>
__global__ __launch_bounds__(256) void lc_mfma(const unsigned short* __restrict__ xb,
                                               const unsigned short* __restrict__ wbT,
                                               const float* __restrict__ bias,
                                               unsigned short* __restrict__ out,
                                               int pos_base, int pos_count) {
  constexpr int KHW = KH * KH;
  constexpr int P = (KHW + 1) / 2;
  constexpr int NPOS = OH * OH;
  const int lane = threadIdx.x & 63;
  const int wvi = threadIdx.x >> 6;
  int unit = blockIdx.x * 4 + wvi;                // lpos*2 + bh
  if (unit >= pos_count * 2) unit = pos_count * 2 - 1;
  const int lpos = unit >> 1, bh = unit & 1;
  const int pos = pos_base + lpos;
  const int oh = pos / OH, ow = pos % OH;
  const int bcol = lane & 15;
  const int kc = lane >> 4;
  const int tsel = kc >> 1;
  const int icoff = (kc & 1) * 8;
  f32x4 acc0 = {0.f, 0.f, 0.f, 0.f};
  const unsigned short* wp = wbT + (size_t)lpos * (P * 512) + bcol * 32 + kc * 8;
  const int xorg = (oh * S) * IH + ow * S;
  const int bload = (bcol + bh * 16) * 16;

  #pragma unroll
  for (int p = 0; p < P; ++p) {
    const int t0 = 2 * p;
    const int t1 = (2 * p + 1 < KHW) ? 2 * p + 1 : 2 * p;
    const int o0 = (t0 / KH) * IH + (t0 % KH);
    const int o1 = (t1 / KH) * IH + (t1 % KH);
    const int osel = tsel ? o1 : o0;
    const bf16x8 a = *(const bf16x8*)(wp + p * 512);
    const bf16x8 b0 =
        *(const bf16x8*)(xb + (size_t)(xorg + osel) * 512 + icoff + bload);
    acc0 = __builtin_amdgcn_mfma_f32_16x16x32_bf16(a, b0, acc0, 0, 0, 0);
  }

  u16x4 pk0;
  #pragma unroll
  for (int r = 0; r < 4; ++r) {
    const float bv = bias[(kc * 4 + r) * NPOS + pos];
    pk0[r] = f2bf(fmaxf(acc0[r] + bv, 0.f));
  }
  *(u16x4*)(out + (size_t)pos * 512 + (bcol + bh * 16) * 16 + kc * 4) = pk0;
}

// ---------------- reformat lc3 out [pos441][b32][oc16] bf16 -> h5T f32 [oc*441+pos][b32]
__global__ __launch_bounds__(256) void fc_reformat(const unsigned short* __restrict__ xb5,
                                                   float* __restrict__ h5T) {
  const int j = blockIdx.x * 256 + threadIdx.x;   // 225792 exact
  const int b = j & 31;
  const int pos = (j >> 5) % 441;
  const int oc = j / (441 * 32);
  h5T[j] = bf2f(xb5[((size_t)pos * 32 + b) * 16 + oc]);
}

// ---------------- fc1 v3: n-split (4 n per block, grid 1024 -> 4096 waves)
__global__ __launch_bounds__(256) void fc1_v3(const float* __restrict__ xt,
                                              const float* __restrict__ w,
                                              const float* __restrict__ bias,
                                              float* __restrict__ out) {
  const int lane = threadIdx.x & 63;
  const int b0 = (threadIdx.x >> 6) * 8;
  const int n0 = blockIdx.x * 4;
  float acc[4][8] = {};
  for (int it = 0; it < 28; ++it) {
    const int kb = it * 256 + lane * 4;
    float4 wf[4], xa[4], xb[4];
    if (kb < 7056) {
      #pragma unroll
      for (int n = 0; n < 4; ++n)
        wf[n] = *(const float4*)&w[(size_t)(n0 + n) * 7056 + kb];
      #pragma unroll
      for (int j = 0; j < 4; ++j) {
        xa[j] = *(const float4*)&xt[(size_t)(kb + j) * 32 + b0];
        xb[j] = *(const float4*)&xt[(size_t)(kb + j) * 32 + b0 + 4];
      }
    } else {
      #pragma unroll
      for (int n = 0; n < 4; ++n) wf[n] = make_float4(0.f, 0.f, 0.f, 0.f);
      #pragma unroll
      for (int j = 0; j < 4; ++j) {
        xa[j] = make_float4(0.f, 0.f, 0.f, 0.f);
        xb[j] = make_float4(0.f, 0.f, 0.f, 0.f);
      }
    }
    #pragma unroll
    for (int n = 0; n < 4; ++n) {
      const float wk[4] = {wf[n].x, wf[n].y, wf[n].z, wf[n].w};
      #pragma unroll
      for (int j = 0; j < 4; ++j) {
        acc[n][0] += wk[j] * xa[j].x;
        acc[n][1] += wk[j] * xa[j].y;
        acc[n][2] += wk[j] * xa[j].z;
        acc[n][3] += wk[j] * xa[j].w;
        acc[n][4] += wk[j] * xb[j].x;
        acc[n][5] += wk[j] * xb[j].y;
        acc[n][6] += wk[j] * xb[j].z;
        acc[n][7] += wk[j] * xb[j].w;
      }
    }
  }
  #pragma unroll
  for (int n = 0; n < 4; ++n)
    #pragma unroll
    for (int c = 0; c < 8; ++c)
      #pragma unroll
      for (int m = 1; m < 64; m <<= 1)
        acc[n][c] += __shfl_xor(acc[n][c], m, 64);
  float val = 0.f;
  #pragma unroll
  for (int n = 0; n < 4; ++n)
    #pragma unroll
    for (int c = 0; c < 8; ++c)
      if (lane == n * 8 + c) val = acc[n][c];
  if (lane < 32) {
    const int n_l = lane >> 3, b_l = lane & 7;
    out[(size_t)(b0 + b_l) * 4096 + n0 + n_l] = val + bias[n0 + n_l];
  }
}

extern "C" void kernel_launch(void* const* d_in, const int* in_sizes, int n_in,
                              void* d_out, int out_size, void* d_ws, size_t ws_size,
                              hipStream_t stream) {
  const float* x       = (const float*)d_in[0];
  const float* conv1_w = (const float*)d_in[1];
  const float* conv1_b = (const float*)d_in[2];
  const float* conv2_w = (const float*)d_in[3];
  const float* conv2_b = (const float*)d_in[4];
  const float* lc1_w   = (const float*)d_in[5];
  const float* lc1_b   = (const float*)d_in[6];
  const float* lc2_w   = (const float*)d_in[7];
  const float* lc2_b   = (const float*)d_in[8];
  const float* lc3_w   = (const float*)d_in[9];
  const float* lc3_b   = (const float*)d_in[10];
  const float* fc1_w   = (const float*)d_in[11];
  const float* fc1_b   = (const float*)d_in[12];
  float* out = (float*)d_out;
  char* ws = (char*)d_ws;

  // timeline-aware layout (bytes), peak ~78.5 MB:
  unsigned short* xb1 = (unsigned short*)(ws + 0);         //  6,225,920 (dead after conv1)
  unsigned short* wb1 = (unsigned short*)(ws + 6291456);   //     34,816
  unsigned short* c1B = (unsigned short*)(ws + 8388608);   // 41,295,872 (dead after pool_t2)
  unsigned short* xb2 = (unsigned short*)(ws + 50331648);  // 10,323,968 (dead after conv2)
  unsigned short* wb2 = (unsigned short*)(ws + 62914560);  //     82,944 (dead after conv2)
  unsigned short* h2b = (unsigned short*)(ws + 67108864);  //  4,064,256 (dead after lc1)
  unsigned short* xb3 = (unsigned short*)(ws + 71303168);  //  3,097,600 (dead after lc2)
  unsigned short* xb4 = (unsigned short*)(ws + 75497472);  //    640,000 (dead after lc3)
  unsigned short* xb5 = (unsigned short*)(ws + 76546048);  //    451,584
  float* h5T          = (float*)(ws + 77594624);           //    903,168
  unsigned short* wbT = (unsigned short*)(ws + 0);         // <= 63,521,792 (lc weight chunks)

  prep_xb1<<<3040, 256, 0, stream>>>(x, xb1);
  prep_wb1<<<68, 256, 0, stream>>>(conv1_w, wb1);
  conv1_mfma<<<5041, 256, 0, stream>>>(xb1, wb1, conv1_b, c1B);
  pool_t2<<<631, 256, 0, stream>>>(c1B, xb2);
  prep_wb2<<<162, 256, 0, stream>>>(conv2_w, wb2);
  conv2_mfma<<<1985, 256, 0, stream>>>(xb2, wb2, conv2_b, h2b);

  // lc1 in two weight chunks (63.5 MB each)
  prep_lcw<9><<<1513, 256, 0, stream>>>(lc1_w, wbT, 0);
  lc_mfma<9, 1, 63, 55><<<757, 256, 0, stream>>>(h2b, wbT, lc1_b, xb3, 0, 1513);
  prep_lcw<9><<<1512, 256, 0, stream>>>(lc1_w, wbT, 1513);
  lc_mfma<9, 1, 63, 55><<<756, 256, 0, stream>>>(h2b, wbT, lc1_b, xb3, 1513, 1512);

  prep_lcw<7><<<625, 256, 0, stream>>>(lc2_w, wbT, 0);
  lc_mfma<7, 2, 55, 25><<<313, 256, 0, stream>>>(xb3, wbT, lc2_b, xb4, 0, 625);

  prep_lcw<5><<<441, 256, 0, stream>>>(lc3_w, wbT, 0);
  lc_mfma<5, 1, 25, 21><<<221, 256, 0, stream>>>(xb4, wbT, lc3_b, xb5, 0, 441);

  fc_reformat<<<882, 256, 0, stream>>>(xb5, h5T);
  fc1_v3<<<1024, 256, 0, stream>>>(h5T, fc1_w, fc1_b, out);
}

// Round 19
// 430.337 us; speedup vs baseline: 1.1589x; 1.1589x over previous
//
#include <hip/hip_runtime.h>
#include <cstddef>

typedef __attribute__((ext_vector_type(8))) short bf16x8;
typedef __attribute__((ext_vector_type(8), aligned(8))) short bf16x8a;
typedef __attribute__((ext_vector_type(4))) float f32x4;
typedef __attribute__((ext_vector_type(4))) unsigned short u16x4;
typedef __attribute__((ext_vector_type(8))) unsigned short u16x8;

__device__ inline unsigned short f2bf(float f) {
  unsigned int u = __float_as_uint(f);
  unsigned int r = (u + 0x7FFFu + ((u >> 16) & 1u)) >> 16;
  return (unsigned short)r;
}
__device__ inline float bf2f(unsigned short u) {
  return __uint_as_float((unsigned int)u << 16);
}

// ---------------- prep: x (32,3,152,152) f32 -> xb1 bf16 [ih152][iw160][b32][ic4]
__global__ __launch_bounds__(256) void prep_xb1(const float* __restrict__ x,
                                                unsigned short* __restrict__ xb) {
  const int j = blockIdx.x * 256 + threadIdx.x;   // 32*152*160 = 778240 exact
  const int iw = j % 160;
  const int ih = (j / 160) % 152;
  const int b = j / (160 * 152);
  unsigned short v[4] = {0, 0, 0, 0};
  if (iw < 152) {
    #pragma unroll
    for (int ic = 0; ic < 3; ++ic)
      v[ic] = f2bf(x[(size_t)(b * 3 + ic) * 23104 + ih * 152 + iw]);
  }
  *(unsigned long long*)(xb + ((((size_t)ih * 160 + iw) * 32) + b) * 4) =
      *(unsigned long long*)v;
}

// ---------------- prep: conv1 w (32,3,11,11) -> A-table wb1 [step17][kc4][s32][8]
__global__ __launch_bounds__(256) void prep_wb1(const float* __restrict__ w,
                                                unsigned short* __restrict__ wb) {
  const int j = blockIdx.x * 256 + threadIdx.x;   // 17408 exact
  const int e = j & 7;
  const int s = (j >> 3) & 31;
  const int kcj = j >> 8;
  const int kc = kcj & 3, step = kcj >> 2;
  const int t = step * 8 + kc * 2 + (e >> 2);
  const int ics = e & 3;
  const int kh = t / 12, kwp = t - kh * 12;
  float val = 0.f;
  if (t < 132 && kwp < 11 && ics < 3)
    val = w[((s * 3 + ics) * 11 + kh) * 11 + kwp];
  wb[j] = f2bf(val);
}

// ---------------- conv1 via MFMA: writes c1B bf16 [pos20164][b32][oc32].
__global__ __launch_bounds__(256, 4) void conv1_mfma(const unsigned short* __restrict__ xb,
                                                     const unsigned short* __restrict__ wb,
                                                     const float* __restrict__ bias,
                                                     unsigned short* __restrict__ outB) {
  const int lane = threadIdx.x & 63;
  const int wvi = threadIdx.x >> 6;
  const int pos = blockIdx.x * 4 + wvi;           // 5041*4 = 20164 exact
  const int oh = pos / 142, ow = pos % 142;
  const int row = lane & 15;
  const int kc = lane >> 4;
  f32x4 a00 = {0.f, 0.f, 0.f, 0.f}, a01 = a00, a10 = a00, a11 = a00;

  #pragma unroll 2
  for (int j = 0; j < 17; ++j) {
    const int t0 = j * 8 + 2 * kc;
    int kh = t0 / 12;
    int kwp = t0 - kh * 12;
    if (t0 >= 132) { kh = 0; kwp = 0; }
    const bf16x8 wa0 = *(const bf16x8*)(wb + (((j * 4 + kc) * 32) + row) * 8);
    const bf16x8 wa1 = *(const bf16x8*)(wb + (((j * 4 + kc) * 32) + 16 + row) * 8);
    const size_t base = (((size_t)(oh + kh) * 160) + (ow + kwp)) * 128;
    const unsigned short* xp0 = xb + base + row * 4;
    bf16x8 xv0, xv1;
    ((unsigned long long*)&xv0)[0] = *(const unsigned long long*)(xp0);
    ((unsigned long long*)&xv0)[1] = *(const unsigned long long*)(xp0 + 128);
    ((unsigned long long*)&xv1)[0] = *(const unsigned long long*)(xp0 + 64);
    ((unsigned long long*)&xv1)[1] = *(const unsigned long long*)(xp0 + 192);
    a00 = __builtin_amdgcn_mfma_f32_16x16x32_bf16(wa0, xv0, a00, 0, 0, 0);
    a01 = __builtin_amdgcn_mfma_f32_16x16x32_bf16(wa0, xv1, a01, 0, 0, 0);
    a10 = __builtin_amdgcn_mfma_f32_16x16x32_bf16(wa1, xv0, a10, 0, 0, 0);
    a11 = __builtin_amdgcn_mfma_f32_16x16x32_bf16(wa1, xv1, a11, 0, 0, 0);
  }

  unsigned short* ob = outB + (size_t)pos * 1024;
  u16x4 p00, p01, p10, p11;
  #pragma unroll
  for (int r = 0; r < 4; ++r) {
    const float bv0 = bias[kc * 4 + r];
    const float bv1 = bias[16 + kc * 4 + r];
    p00[r] = f2bf(fmaxf(a00[r] + bv0, 0.f));
    p01[r] = f2bf(fmaxf(a01[r] + bv0, 0.f));
    p10[r] = f2bf(fmaxf(a10[r] + bv1, 0.f));
    p11[r] = f2bf(fmaxf(a11[r] + bv1, 0.f));
  }
  *(u16x4*)(ob + row * 32 + kc * 4) = p00;
  *(u16x4*)(ob + (row + 16) * 32 + kc * 4) = p01;
  *(u16x4*)(ob + row * 32 + 16 + kc * 4) = p10;
  *(u16x4*)(ob + (row + 16) * 32 + 16 + kc * 4) = p11;
}

// ---------------- pool_t2: maxpool(3,2,1) on c1B [pos][b32][oc32] -> xb2
// [pos'5041][b32][ic32]. Integer max valid (relu >= 0).
__global__ __launch_bounds__(256) void pool_t2(const unsigned short* __restrict__ in,
                                               unsigned short* __restrict__ xb) {
  const int tid = threadIdx.x;
  const int b = tid & 31, pg = tid >> 5;
  const int posp = blockIdx.x * 8 + pg;
  if (posp >= 5041) return;
  const int ohp = posp / 71, owp = posp % 71;
  u16x8 m[4];
  #pragma unroll
  for (int q = 0; q < 4; ++q)
    #pragma unroll
    for (int e = 0; e < 8; ++e) m[q][e] = 0;

  #pragma unroll
  for (int kh = 0; kh < 3; ++kh) {
    const int ih = ohp * 2 - 1 + kh;
    if (ih < 0 || ih >= 142) continue;
    #pragma unroll
    for (int kw = 0; kw < 3; ++kw) {
      const int iw = owp * 2 - 1 + kw;
      if (iw < 0 || iw >= 142) continue;
      const u16x8* p =
          (const u16x8*)(in + (((size_t)(ih * 142 + iw)) * 32 + b) * 32);
      #pragma unroll
      for (int q = 0; q < 4; ++q) {
        const u16x8 v = p[q];
        #pragma unroll
        for (int e = 0; e < 8; ++e) m[q][e] = (v[e] > m[q][e]) ? v[e] : m[q][e];
      }
    }
  }
  u16x8* o = (u16x8*)(xb + ((size_t)posp * 32 + b) * 32);
  #pragma unroll
  for (int q = 0; q < 4; ++q) o[q] = m[q];
}

// ---------------- wb2: conv2 w (16,32,9,9) -> [sp81][oc16][ic32] bf16
__global__ __launch_bounds__(256) void prep_wb2(const float* __restrict__ w,
                                                unsigned short* __restrict__ wb) {
  const int j = blockIdx.x * 256 + threadIdx.x;
  if (j >= 81 * 16 * 32) return;
  const int ic = j & 31, oc = (j >> 5) & 15, sp = j >> 9;
  wb[j] = f2bf(w[(size_t)oc * 2592 + ic * 81 + sp]);
}

// ---------------- conv2 via MFMA (round-17 version); writes h2b bf16 [pos][b32][oc16]
__global__ __launch_bounds__(256) void conv2_mfma(const unsigned short* __restrict__ xb,
                                                  const unsigned short* __restrict__ wb,
                                                  const float* __restrict__ bias,
                                                  unsigned short* __restrict__ outB) {
  const int lane = threadIdx.x & 63;
  const int wvi = threadIdx.x >> 6;
  int pos = blockIdx.x * 4 + wvi;
  if (pos > 3968) pos = 3968;
  const int oh = pos / 63, ow = pos % 63;
  const int row = lane & 15;                      // b column
  const int kc = lane >> 4;
  f32x4 acc0 = {0.f, 0.f, 0.f, 0.f}, acc1 = {0.f, 0.f, 0.f, 0.f};
  const unsigned short* xbase = xb + (size_t)(oh * 71 + ow) * 1024;
  const int aoff = row * 32 + kc * 8;
  const int boff0 = aoff;
  const int boff1 = (row + 16) * 32 + kc * 8;

  #pragma unroll
  for (int kh = 0; kh < 9; ++kh) {
    #pragma unroll
    for (int kw = 0; kw < 9; ++kw) {
      const int sp = kh * 9 + kw;
      const bf16x8 a = *(const bf16x8*)(wb + sp * 512 + aoff);
      const unsigned short* xp = xbase + (kh * 71 + kw) * 1024;
      const bf16x8 b0 = *(const bf16x8*)(xp + boff0);
      const bf16x8 b1 = *(const bf16x8*)(xp + boff1);
      acc0 = __builtin_amdgcn_mfma_f32_16x16x32_bf16(a, b0, acc0, 0, 0, 0);
      acc1 = __builtin_amdgcn_mfma_f32_16x16x32_bf16(a, b1, acc1, 0, 0, 0);
    }
  }

  u16x4 pk0, pk1;
  #pragma unroll
  for (int r = 0; r < 4; ++r) {
    const float bv = bias[kc * 4 + r];
    pk0[r] = f2bf(fmaxf(acc0[r] + bv, 0.f));
    pk1[r] = f2bf(fmaxf(acc1[r] + bv, 0.f));
  }
  *(u16x4*)(outB + (size_t)pos * 512 + row * 16 + kc * 4) = pk0;
  *(u16x4*)(outB + (size_t)pos * 512 + (row + 16) * 16 + kc * 4) = pk1;
}

// ---------------- lc weight prep: w [pos][oc16][ic16][KHW] f32 ->
// wbT bf16 [lpos][pair][oc16][tl2*ic16]; LDS-staged, coalesced read+write.
template <int KH>
__global__ __launch_bounds__(256) void prep_lcw(const float* __restrict__ w,
                                                unsigned short* __restrict__ wbT,
                                                int pos_base) {
  constexpr int KHW = KH * KH;
  constexpr int P = (KHW + 1) / 2;
  __shared__ float ls[8 * 16 * KHW];
  const int tid = threadIdx.x;
  const float* wp = w + (size_t)(pos_base + blockIdx.x) * (256 * KHW);
  unsigned short* ob = wbT + (size_t)blockIdx.x * (P * 512);

  for (int half = 0; half < 2; ++half) {
    __syncthreads();
    for (int j = tid; j < 8 * 16 * KHW; j += 256)
      ls[j] = wp[half * (8 * 16 * KHW) + j];
    __syncthreads();
    for (int j = tid; j < P * 256; j += 256) {
      const int ic = j & 15, tl = (j >> 4) & 1, oc8 = (j >> 5) & 7, pair = j >> 8;
      const int tap = pair * 2 + tl;
      const float v = (tap < KHW) ? ls[(oc8 * 16 + ic) * KHW + tap] : 0.f;
      ob[(size_t)pair * 512 + (half * 8 + oc8) * 32 + tl * 16 + ic] = f2bf(v);
    }
  }
}

// ---------------- lc via MFMA (round-17 version): wave = 1 pos; K = 2 taps x 16 ic.
template <int KH, int S, int IH, int OH>
__global__ __launch_bounds__(256) void lc_mfma(const unsigned short* __restrict__ xb,
                                               const unsigned short* __restrict__ wbT,
                                               const float* __restrict__ bias,
                                               unsigned short* __restrict__ out,
                                               int pos_base, int pos_count) {
  constexpr int KHW = KH * KH;
  constexpr int P = (KHW + 1) / 2;
  constexpr int NPOS = OH * OH;
  const int lane = threadIdx.x & 63;
  const int wvi = threadIdx.x >> 6;
  int lpos = blockIdx.x * 4 + wvi;
  if (lpos >= pos_count) lpos = pos_count - 1;
  const int pos = pos_base + lpos;
  const int oh = pos / OH, ow = pos % OH;
  const int bcol = lane & 15;
  const int kc = lane >> 4;
  const int tsel = kc >> 1;
  const int icoff = (kc & 1) * 8;
  f32x4 acc0 = {0.f, 0.f, 0.f, 0.f}, acc1 = {0.f, 0.f, 0.f, 0.f};
  const unsigned short* wp = wbT + (size_t)lpos * (P * 512) + bcol * 32 + kc * 8;
  const int xorg = (oh * S) * IH + ow * S;

  #pragma unroll
  for (int p = 0; p < P; ++p) {
    const int t0 = 2 * p;
    const int t1 = (2 * p + 1 < KHW) ? 2 * p + 1 : 2 * p;
    const int o0 = (t0 / KH) * IH + (t0 % KH);
    const int o1 = (t1 / KH) * IH + (t1 % KH);
    const int osel = tsel ? o1 : o0;
    const bf16x8 a = *(const bf16x8*)(wp + p * 512);
    const unsigned short* xp = xb + (size_t)(xorg + osel) * 512 + icoff;
    const bf16x8 b0 = *(const bf16x8*)(xp + bcol * 16);
    const bf16x8 b1 = *(const bf16x8*)(xp + (bcol + 16) * 16);
    acc0 = __builtin_amdgcn_mfma_f32_16x16x32_bf16(a, b0, acc0, 0, 0, 0);
    acc1 = __builtin_amdgcn_mfma_f32_16x16x32_bf16(a, b1, acc1, 0, 0, 0);
  }

  u16x4 pk0, pk1;
  #pragma unroll
  for (int r = 0; r < 4; ++r) {
    const float bv = bias[(kc * 4 + r) * NPOS + pos];
    pk0[r] = f2bf(fmaxf(acc0[r] + bv, 0.f));
    pk1[r] = f2bf(fmaxf(acc1[r] + bv, 0.f));
  }
  *(u16x4*)(out + (size_t)pos * 512 + bcol * 16 + kc * 4) = pk0;
  *(u16x4*)(out + (size_t)pos * 512 + (bcol + 16) * 16 + kc * 4) = pk1;
}

// ---------------- reformat lc3 out [pos441][b32][oc16] bf16 -> h5T f32 [oc*441+pos][b32]
__global__ __launch_bounds__(256) void fc_reformat(const unsigned short* __restrict__ xb5,
                                                   float* __restrict__ h5T) {
  const int j = blockIdx.x * 256 + threadIdx.x;   // 225792 exact
  const int b = j & 31;
  const int pos = (j >> 5) % 441;
  const int oc = j / (441 * 32);
  h5T[j] = bf2f(xb5[((size_t)pos * 32 + b) * 16 + oc]);
}

// ---------------- fc1 v4: K-split x4 (grid 512x4 = 8192 waves), 8x8 reg tile,
// fully-coalesced w reads, 16 loads in flight per iteration. Partials f32.
__global__ __launch_bounds__(256) void fc1_v4(const float* __restrict__ xt,
                                              const float* __restrict__ w,
                                              float* __restrict__ part) {
  const int lane = threadIdx.x & 63;
  const int b0 = (threadIdx.x >> 6) * 8;
  const int n0 = blockIdx.x * 8;
  const int kch = blockIdx.y;                     // 0..3
  const int kbase = kch * 1764;                   // 1764 = 7056/4 (mult of 4)
  float acc[8][8] = {};
  for (int it = 0; it < 7; ++it) {
    const int ko = it * 256 + lane * 4;
    const int kb = kbase + ko;
    float4 wf[8], xa[4], xb[4];
    if (ko < 1764) {
      #pragma unroll
      for (int n = 0; n < 8; ++n)
        wf[n] = *(const float4*)&w[(size_t)(n0 + n) * 7056 + kb];
      #pragma unroll
      for (int j = 0; j < 4; ++j) {
        xa[j] = *(const float4*)&xt[(size_t)(kb + j) * 32 + b0];
        xb[j] = *(const float4*)&xt[(size_t)(kb + j) * 32 + b0 + 4];
      }
    } else {
      #pragma unroll
      for (int n = 0; n < 8; ++n) wf[n] = make_float4(0.f, 0.f, 0.f, 0.f);
      #pragma unroll
      for (int j = 0; j < 4; ++j) {
        xa[j] = make_float4(0.f, 0.f, 0.f, 0.f);
        xb[j] = make_float4(0.f, 0.f, 0.f, 0.f);
      }
    }
    #pragma unroll
    for (int n = 0; n < 8; ++n) {
      const float wk[4] = {wf[n].x, wf[n].y, wf[n].z, wf[n].w};
      #pragma unroll
      for (int j = 0; j < 4; ++j) {
        acc[n][0] += wk[j] * xa[j].x;
        acc[n][1] += wk[j] * xa[j].y;
        acc[n][2] += wk[j] * xa[j].z;
        acc[n][3] += wk[j] * xa[j].w;
        acc[n][4] += wk[j] * xb[j].x;
        acc[n][5] += wk[j] * xb[j].y;
        acc[n][6] += wk[j] * xb[j].z;
        acc[n][7] += wk[j] * xb[j].w;
      }
    }
  }
  #pragma unroll
  for (int n = 0; n < 8; ++n)
    #pragma unroll
    for (int c = 0; c < 8; ++c)
      #pragma unroll
      for (int m = 1; m < 64; m <<= 1)
        acc[n][c] += __shfl_xor(acc[n][c], m, 64);
  float val = 0.f;
  #pragma unroll
  for (int n = 0; n < 8; ++n)
    #pragma unroll
    for (int c = 0; c < 8; ++c)
      if (lane == n * 8 + c) val = acc[n][c];
  const int n_l = lane >> 3, b_l = lane & 7;
  part[(((size_t)kch * 4096 + n0 + n_l) * 32) + b0 + b_l] = val;
}

// combine 4 K-partials + bias -> out (32,4096); coalesced over n.
__global__ __launch_bounds__(256) void fc_combine(const float* __restrict__ part,
                                                  const float* __restrict__ bias,
                                                  float* __restrict__ out) {
  const int j = blockIdx.x * 256 + threadIdx.x;   // 131072 exact
  const int n = j & 4095, b = j >> 12;
  float v = bias[n];
  #pragma unroll
  for (int k = 0; k < 4; ++k) v += part[(((size_t)k * 4096 + n) * 32) + b];
  out[(size_t)b * 4096 + n] = v;
}

extern "C" void kernel_launch(void* const* d_in, const int* in_sizes, int n_in,
                              void* d_out, int out_size, void* d_ws, size_t ws_size,
                              hipStream_t stream) {
  const float* x       = (const float*)d_in[0];
  const float* conv1_w = (const float*)d_in[1];
  const float* conv1_b = (const float*)d_in[2];
  const float* conv2_w = (const float*)d_in[3];
  const float* conv2_b = (const float*)d_in[4];
  const float* lc1_w   = (const float*)d_in[5];
  const float* lc1_b   = (const float*)d_in[6];
  const float* lc2_w   = (const float*)d_in[7];
  const float* lc2_b   = (const float*)d_in[8];
  const float* lc3_w   = (const float*)d_in[9];
  const float* lc3_b   = (const float*)d_in[10];
  const float* fc1_w   = (const float*)d_in[11];
  const float* fc1_b   = (const float*)d_in[12];
  float* out = (float*)d_out;
  char* ws = (char*)d_ws;

  // timeline-aware layout (bytes), peak ~80.6 MB:
  unsigned short* xb1 = (unsigned short*)(ws + 0);         //  6,225,920 (dead after conv1)
  unsigned short* wb1 = (unsigned short*)(ws + 6291456);   //     34,816
  unsigned short* c1B = (unsigned short*)(ws + 8388608);   // 41,295,872 (dead after pool_t2)
  unsigned short* xb2 = (unsigned short*)(ws + 50331648);  // 10,323,968 (dead after conv2)
  unsigned short* wb2 = (unsigned short*)(ws + 62914560);  //     82,944 (dead after conv2)
  unsigned short* h2b = (unsigned short*)(ws + 67108864);  //  4,064,256 (dead after lc1)
  unsigned short* xb3 = (unsigned short*)(ws + 71303168);  //  3,097,600 (dead after lc2)
  unsigned short* xb4 = (unsigned short*)(ws + 75497472);  //    640,000 (dead after lc3)
  unsigned short* xb5 = (unsigned short*)(ws + 76546048);  //    451,584
  float* h5T          = (float*)(ws + 77594624);           //    903,168
  float* fcp          = (float*)(ws + 78643200);           //  2,097,152 (fc1 partials)
  unsigned short* wbT = (unsigned short*)(ws + 0);         // <= 63,521,792 (lc weight chunks)

  prep_xb1<<<3040, 256, 0, stream>>>(x, xb1);
  prep_wb1<<<68, 256, 0, stream>>>(conv1_w, wb1);
  conv1_mfma<<<5041, 256, 0, stream>>>(xb1, wb1, conv1_b, c1B);
  pool_t2<<<631, 256, 0, stream>>>(c1B, xb2);
  prep_wb2<<<162, 256, 0, stream>>>(conv2_w, wb2);
  conv2_mfma<<<993, 256, 0, stream>>>(xb2, wb2, conv2_b, h2b);

  // lc1 in two weight chunks (63.5 MB each)
  prep_lcw<9><<<1513, 256, 0, stream>>>(lc1_w, wbT, 0);
  lc_mfma<9, 1, 63, 55><<<379, 256, 0, stream>>>(h2b, wbT, lc1_b, xb3, 0, 1513);
  prep_lcw<9><<<1512, 256, 0, stream>>>(lc1_w, wbT, 1513);
  lc_mfma<9, 1, 63, 55><<<378, 256, 0, stream>>>(h2b, wbT, lc1_b, xb3, 1513, 1512);

  prep_lcw<7><<<625, 256, 0, stream>>>(lc2_w, wbT, 0);
  lc_mfma<7, 2, 55, 25><<<157, 256, 0, stream>>>(xb3, wbT, lc2_b, xb4, 0, 625);

  prep_lcw<5><<<441, 256, 0, stream>>>(lc3_w, wbT, 0);
  lc_mfma<5, 1, 25, 21><<<111, 256, 0, stream>>>(xb4, wbT, lc3_b, xb5, 0, 441);

  fc_reformat<<<882, 256, 0, stream>>>(xb5, h5T);
  fc1_v4<<<dim3(512, 4), 256, 0, stream>>>(h5T, fc1_w, fcp);
  fc_combine<<<512, 256, 0, stream>>>(fcp, fc1_b, out);
}

// Round 20
// 401.895 us; speedup vs baseline: 1.2409x; 1.0708x over previous
//
#include <hip/hip_runtime.h>
#include <cstddef>

typedef __attribute__((ext_vector_type(8))) short bf16x8;
typedef __attribute__((ext_vector_type(8), aligned(8))) short bf16x8a;
typedef __attribute__((ext_vector_type(4))) float f32x4;
typedef __attribute__((ext_vector_type(4))) unsigned short u16x4;
typedef __attribute__((ext_vector_type(8))) unsigned short u16x8;

__device__ inline unsigned short f2bf(float f) {
  unsigned int u = __float_as_uint(f);
  unsigned int r = (u + 0x7FFFu + ((u >> 16) & 1u)) >> 16;
  return (unsigned short)r;
}
__device__ inline float bf2f(unsigned short u) {
  return __uint_as_float((unsigned int)u << 16);
}

// ---------------- prep: x (32,3,152,152) f32 -> xb1 bf16 [ih152][iw160][b32][ic4]
__global__ __launch_bounds__(256) void prep_xb1(const float* __restrict__ x,
                                                unsigned short* __restrict__ xb) {
  const int j = blockIdx.x * 256 + threadIdx.x;   // 32*152*160 = 778240 exact
  const int iw = j % 160;
  const int ih = (j / 160) % 152;
  const int b = j / (160 * 152);
  unsigned short v[4] = {0, 0, 0, 0};
  if (iw < 152) {
    #pragma unroll
    for (int ic = 0; ic < 3; ++ic)
      v[ic] = f2bf(x[(size_t)(b * 3 + ic) * 23104 + ih * 152 + iw]);
  }
  *(unsigned long long*)(xb + ((((size_t)ih * 160 + iw) * 32) + b) * 4) =
      *(unsigned long long*)v;
}

// ---------------- prep: conv1 w (32,3,11,11) -> A-table wb1 [step17][kc4][s32][8]
__global__ __launch_bounds__(256) void prep_wb1(const float* __restrict__ w,
                                                unsigned short* __restrict__ wb) {
  const int j = blockIdx.x * 256 + threadIdx.x;   // 17408 exact
  const int e = j & 7;
  const int s = (j >> 3) & 31;
  const int kcj = j >> 8;
  const int kc = kcj & 3, step = kcj >> 2;
  const int t = step * 8 + kc * 2 + (e >> 2);
  const int ics = e & 3;
  const int kh = t / 12, kwp = t - kh * 12;
  float val = 0.f;
  if (t < 132 && kwp < 11 && ics < 3)
    val = w[((s * 3 + ics) * 11 + kh) * 11 + kwp];
  wb[j] = f2bf(val);
}

// ---------------- conv1 via MFMA: writes c1B bf16 [pos20164][b32][oc32].
__global__ __launch_bounds__(256, 4) void conv1_mfma(const unsigned short* __restrict__ xb,
                                                     const unsigned short* __restrict__ wb,
                                                     const float* __restrict__ bias,
                                                     unsigned short* __restrict__ outB) {
  const int lane = threadIdx.x & 63;
  const int wvi = threadIdx.x >> 6;
  const int pos = blockIdx.x * 4 + wvi;           // 5041*4 = 20164 exact
  const int oh = pos / 142, ow = pos % 142;
  const int row = lane & 15;
  const int kc = lane >> 4;
  f32x4 a00 = {0.f, 0.f, 0.f, 0.f}, a01 = a00, a10 = a00, a11 = a00;

  #pragma unroll 2
  for (int j = 0; j < 17; ++j) {
    const int t0 = j * 8 + 2 * kc;
    int kh = t0 / 12;
    int kwp = t0 - kh * 12;
    if (t0 >= 132) { kh = 0; kwp = 0; }
    const bf16x8 wa0 = *(const bf16x8*)(wb + (((j * 4 + kc) * 32) + row) * 8);
    const bf16x8 wa1 = *(const bf16x8*)(wb + (((j * 4 + kc) * 32) + 16 + row) * 8);
    const size_t base = (((size_t)(oh + kh) * 160) + (ow + kwp)) * 128;
    const unsigned short* xp0 = xb + base + row * 4;
    bf16x8 xv0, xv1;
    ((unsigned long long*)&xv0)[0] = *(const unsigned long long*)(xp0);
    ((unsigned long long*)&xv0)[1] = *(const unsigned long long*)(xp0 + 128);
    ((unsigned long long*)&xv1)[0] = *(const unsigned long long*)(xp0 + 64);
    ((unsigned long long*)&xv1)[1] = *(const unsigned long long*)(xp0 + 192);
    a00 = __builtin_amdgcn_mfma_f32_16x16x32_bf16(wa0, xv0, a00, 0, 0, 0);
    a01 = __builtin_amdgcn_mfma_f32_16x16x32_bf16(wa0, xv1, a01, 0, 0, 0);
    a10 = __builtin_amdgcn_mfma_f32_16x16x32_bf16(wa1, xv0, a10, 0, 0, 0);
    a11 = __builtin_amdgcn_mfma_f32_16x16x32_bf16(wa1, xv1, a11, 0, 0, 0);
  }

  unsigned short* ob = outB + (size_t)pos * 1024;
  u16x4 p00, p01, p10, p11;
  #pragma unroll
  for (int r = 0; r < 4; ++r) {
    const float bv0 = bias[kc * 4 + r];
    const float bv1 = bias[16 + kc * 4 + r];
    p00[r] = f2bf(fmaxf(a00[r] + bv0, 0.f));
    p01[r] = f2bf(fmaxf(a01[r] + bv0, 0.f));
    p10[r] = f2bf(fmaxf(a10[r] + bv1, 0.f));
    p11[r] = f2bf(fmaxf(a11[r] + bv1, 0.f));
  }
  *(u16x4*)(ob + row * 32 + kc * 4) = p00;
  *(u16x4*)(ob + (row + 16) * 32 + kc * 4) = p01;
  *(u16x4*)(ob + row * 32 + 16 + kc * 4) = p10;
  *(u16x4*)(ob + (row + 16) * 32 + 16 + kc * 4) = p11;
}

// ---------------- pool_t2: maxpool(3,2,1) on c1B [pos][b32][oc32] -> xb2
// [pos'5041][b32][ic32]. Integer max valid (relu >= 0).
__global__ __launch_bounds__(256) void pool_t2(const unsigned short* __restrict__ in,
                                               unsigned short* __restrict__ xb) {
  const int tid = threadIdx.x;
  const int b = tid & 31, pg = tid >> 5;
  const int posp = blockIdx.x * 8 + pg;
  if (posp >= 5041) return;
  const int ohp = posp / 71, owp = posp % 71;
  u16x8 m[4];
  #pragma unroll
  for (int q = 0; q < 4; ++q)
    #pragma unroll
    for (int e = 0; e < 8; ++e) m[q][e] = 0;

  #pragma unroll
  for (int kh = 0; kh < 3; ++kh) {
    const int ih = ohp * 2 - 1 + kh;
    if (ih < 0 || ih >= 142) continue;
    #pragma unroll
    for (int kw = 0; kw < 3; ++kw) {
      const int iw = owp * 2 - 1 + kw;
      if (iw < 0 || iw >= 142) continue;
      const u16x8* p =
          (const u16x8*)(in + (((size_t)(ih * 142 + iw)) * 32 + b) * 32);
      #pragma unroll
      for (int q = 0; q < 4; ++q) {
        const u16x8 v = p[q];
        #pragma unroll
        for (int e = 0; e < 8; ++e) m[q][e] = (v[e] > m[q][e]) ? v[e] : m[q][e];
      }
    }
  }
  u16x8* o = (u16x8*)(xb + ((size_t)posp * 32 + b) * 32);
  #pragma unroll
  for (int q = 0; q < 4; ++q) o[q] = m[q];
}

// ---------------- wb2: conv2 w (16,32,9,9) -> [sp81][oc16][ic32] bf16
__global__ __launch_bounds__(256) void prep_wb2(const float* __restrict__ w,
                                                unsigned short* __restrict__ wb) {
  const int j = blockIdx.x * 256 + threadIdx.x;
  if (j >= 81 * 16 * 32) return;
  const int ic = j & 31, oc = (j >> 5) & 15, sp = j >> 9;
  wb[j] = f2bf(w[(size_t)oc * 2592 + ic * 81 + sp]);
}

// ---------------- conv2 via MFMA; writes h2b bf16 [pos][b32][oc16]
__global__ __launch_bounds__(256) void conv2_mfma(const unsigned short* __restrict__ xb,
                                                  const unsigned short* __restrict__ wb,
                                                  const float* __restrict__ bias,
                                                  unsigned short* __restrict__ outB) {
  const int lane = threadIdx.x & 63;
  const int wvi = threadIdx.x >> 6;
  int pos = blockIdx.x * 4 + wvi;
  if (pos > 3968) pos = 3968;
  const int oh = pos / 63, ow = pos % 63;
  const int row = lane & 15;                      // b column
  const int kc = lane >> 4;
  f32x4 acc0 = {0.f, 0.f, 0.f, 0.f}, acc1 = {0.f, 0.f, 0.f, 0.f};
  const unsigned short* xbase = xb + (size_t)(oh * 71 + ow) * 1024;
  const int aoff = row * 32 + kc * 8;
  const int boff0 = aoff;
  const int boff1 = (row + 16) * 32 + kc * 8;

  #pragma unroll
  for (int kh = 0; kh < 9; ++kh) {
    #pragma unroll
    for (int kw = 0; kw < 9; ++kw) {
      const int sp = kh * 9 + kw;
      const bf16x8 a = *(const bf16x8*)(wb + sp * 512 + aoff);
      const unsigned short* xp = xbase + (kh * 71 + kw) * 1024;
      const bf16x8 b0 = *(const bf16x8*)(xp + boff0);
      const bf16x8 b1 = *(const bf16x8*)(xp + boff1);
      acc0 = __builtin_amdgcn_mfma_f32_16x16x32_bf16(a, b0, acc0, 0, 0, 0);
      acc1 = __builtin_amdgcn_mfma_f32_16x16x32_bf16(a, b1, acc1, 0, 0, 0);
    }
  }

  u16x4 pk0, pk1;
  #pragma unroll
  for (int r = 0; r < 4; ++r) {
    const float bv = bias[kc * 4 + r];
    pk0[r] = f2bf(fmaxf(acc0[r] + bv, 0.f));
    pk1[r] = f2bf(fmaxf(acc1[r] + bv, 0.f));
  }
  *(u16x4*)(outB + (size_t)pos * 512 + row * 16 + kc * 4) = pk0;
  *(u16x4*)(outB + (size_t)pos * 512 + (row + 16) * 16 + kc * 4) = pk1;
}

// ---------------- lc weight prep: w [pos][oc16][ic16][KHW] f32 ->
// wbT bf16 [lpos][pair][oc16][tl2*ic16]; LDS-staged, coalesced read+write.
template <int KH>
__global__ __launch_bounds__(256) void prep_lcw(const float* __restrict__ w,
                                                unsigned short* __restrict__ wbT,
                                                int pos_base) {
  constexpr int KHW = KH * KH;
  constexpr int P = (KHW + 1) / 2;
  __shared__ float ls[8 * 16 * KHW];
  const int tid = threadIdx.x;
  const float* wp = w + (size_t)(pos_base + blockIdx.x) * (256 * KHW);
  unsigned short* ob = wbT + (size_t)blockIdx.x * (P * 512);

  for (int half = 0; half < 2; ++half) {
    __syncthreads();
    for (int j = tid; j < 8 * 16 * KHW; j += 256)
      ls[j] = wp[half * (8 * 16 * KHW) + j];
    __syncthreads();
    for (int j = tid; j < P * 256; j += 256) {
      const int ic = j & 15, tl = (j >> 4) & 1, oc8 = (j >> 5) & 7, pair = j >> 8;
      const int tap = pair * 2 + tl;
      const float v = (tap < KHW) ? ls[(oc8 * 16 + ic) * KHW + tap] : 0.f;
      ob[(size_t)pair * 512 + (half * 8 + oc8) * 32 + tl * 16 + ic] = f2bf(v);
    }
  }
}

// ---------------- lc via MFMA: wave = 1 pos; K = 2 taps x 16 ic per step.
template <int KH, int S, int IH, int OH>
__global__ __launch_bounds__(256) void lc_mfma(const unsigned short* __restrict__ xb,
                                               const unsigned short* __restrict__ wbT,
                                               const float* __restrict__ bias,
                                               unsigned short* __restrict__ out,
                                               int pos_base, int pos_count) {
  constexpr int KHW = KH * KH;
  constexpr int P = (KHW + 1) / 2;
  constexpr int NPOS = OH * OH;
  const int lane = threadIdx.x & 63;
  const int wvi = threadIdx.x >> 6;
  int lpos = blockIdx.x * 4 + wvi;
  if (lpos >= pos_count) lpos = pos_count - 1;
  const int pos = pos_base + lpos;
  const int oh = pos / OH, ow = pos % OH;
  const int bcol = lane & 15;
  const int kc = lane >> 4;
  const int tsel = kc >> 1;
  const int icoff = (kc & 1) * 8;
  f32x4 acc0 = {0.f, 0.f, 0.f, 0.f}, acc1 = {0.f, 0.f, 0.f, 0.f};
  const unsigned short* wp = wbT + (size_t)lpos * (P * 512) + bcol * 32 + kc * 8;
  const int xorg = (oh * S) * IH + ow * S;

  #pragma unroll
  for (int p = 0; p < P; ++p) {
    const int t0 = 2 * p;
    const int t1 = (2 * p + 1 < KHW) ? 2 * p + 1 : 2 * p;
    const int o0 = (t0 / KH) * IH + (t0 % KH);
    const int o1 = (t1 / KH) * IH + (t1 % KH);
    const int osel = tsel ? o1 : o0;
    const bf16x8 a = *(const bf16x8*)(wp + p * 512);
    const unsigned short* xp = xb + (size_t)(xorg + osel) * 512 + icoff;
    const bf16x8 b0 = *(const bf16x8*)(xp + bcol * 16);
    const bf16x8 b1 = *(const bf16x8*)(xp + (bcol + 16) * 16);
    acc0 = __builtin_amdgcn_mfma_f32_16x16x32_bf16(a, b0, acc0, 0, 0, 0);
    acc1 = __builtin_amdgcn_mfma_f32_16x16x32_bf16(a, b1, acc1, 0, 0, 0);
  }

  u16x4 pk0, pk1;
  #pragma unroll
  for (int r = 0; r < 4; ++r) {
    const float bv = bias[(kc * 4 + r) * NPOS + pos];
    pk0[r] = f2bf(fmaxf(acc0[r] + bv, 0.f));
    pk1[r] = f2bf(fmaxf(acc1[r] + bv, 0.f));
  }
  *(u16x4*)(out + (size_t)pos * 512 + bcol * 16 + kc * 4) = pk0;
  *(u16x4*)(out + (size_t)pos * 512 + (bcol + 16) * 16 + kc * 4) = pk1;
}

// ---------------- reformat lc3 out [pos441][b32][oc16] bf16 -> xB f32 [b][k7056]
// (k = oc*441 + pos, matching the reference reshape). Coalesced writes.
__global__ __launch_bounds__(256) void fc_reformat2(const unsigned short* __restrict__ xb5,
                                                    float* __restrict__ xB) {
  const int j = blockIdx.x * 256 + threadIdx.x;   // 225792 exact
  const int k = j % 7056;
  const int b = j / 7056;
  const int oc = k / 441, pos = k % 441;
  xB[j] = bf2f(xb5[((size_t)pos * 32 + b) * 16 + oc]);
}

// ---------------- fc1 v5: K-split x4, x in [b][k] layout -> ALL loads coalesced.
__global__ __launch_bounds__(256) void fc1_v5(const float* __restrict__ xB,
                                              const float* __restrict__ w,
                                              float* __restrict__ part) {
  const int lane = threadIdx.x & 63;
  const int b0 = (threadIdx.x >> 6) * 8;
  const int n0 = blockIdx.x * 8;
  const int kch = blockIdx.y;                     // 0..3
  const int kbase = kch * 1764;
  float acc[8][8] = {};
  for (int it = 0; it < 7; ++it) {
    const int ko = it * 256 + lane * 4;
    const int kb = kbase + ko;
    float4 wf[8], xr[8];
    if (ko < 1764) {
      #pragma unroll
      for (int n = 0; n < 8; ++n)
        wf[n] = *(const float4*)&w[(size_t)(n0 + n) * 7056 + kb];
      #pragma unroll
      for (int bb = 0; bb < 8; ++bb)
        xr[bb] = *(const float4*)&xB[(size_t)(b0 + bb) * 7056 + kb];
    } else {
      #pragma unroll
      for (int n = 0; n < 8; ++n) wf[n] = make_float4(0.f, 0.f, 0.f, 0.f);
      #pragma unroll
      for (int bb = 0; bb < 8; ++bb) xr[bb] = make_float4(0.f, 0.f, 0.f, 0.f);
    }
    #pragma unroll
    for (int n = 0; n < 8; ++n)
      #pragma unroll
      for (int bb = 0; bb < 8; ++bb) {
        acc[n][bb] += wf[n].x * xr[bb].x + wf[n].y * xr[bb].y +
                      wf[n].z * xr[bb].z + wf[n].w * xr[bb].w;
      }
  }
  #pragma unroll
  for (int n = 0; n < 8; ++n)
    #pragma unroll
    for (int c = 0; c < 8; ++c)
      #pragma unroll
      for (int m = 1; m < 64; m <<= 1)
        acc[n][c] += __shfl_xor(acc[n][c], m, 64);
  float val = 0.f;
  #pragma unroll
  for (int n = 0; n < 8; ++n)
    #pragma unroll
    for (int c = 0; c < 8; ++c)
      if (lane == n * 8 + c) val = acc[n][c];
  const int n_l = lane >> 3, b_l = lane & 7;
  part[(((size_t)kch * 4096 + n0 + n_l) * 32) + b0 + b_l] = val;
}

// combine 4 K-partials + bias -> out (32,4096); coalesced over n.
__global__ __launch_bounds__(256) void fc_combine(const float* __restrict__ part,
                                                  const float* __restrict__ bias,
                                                  float* __restrict__ out) {
  const int j = blockIdx.x * 256 + threadIdx.x;   // 131072 exact
  const int n = j & 4095, b = j >> 12;
  float v = bias[n];
  #pragma unroll
  for (int k = 0; k < 4; ++k) v += part[(((size_t)k * 4096 + n) * 32) + b];
  out[(size_t)b * 4096 + n] = v;
}

extern "C" void kernel_launch(void* const* d_in, const int* in_sizes, int n_in,
                              void* d_out, int out_size, void* d_ws, size_t ws_size,
                              hipStream_t stream) {
  const float* x       = (const float*)d_in[0];
  const float* conv1_w = (const float*)d_in[1];
  const float* conv1_b = (const float*)d_in[2];
  const float* conv2_w = (const float*)d_in[3];
  const float* conv2_b = (const float*)d_in[4];
  const float* lc1_w   = (const float*)d_in[5];
  const float* lc1_b   = (const float*)d_in[6];
  const float* lc2_w   = (const float*)d_in[7];
  const float* lc2_b   = (const float*)d_in[8];
  const float* lc3_w   = (const float*)d_in[9];
  const float* lc3_b   = (const float*)d_in[10];
  const float* fc1_w   = (const float*)d_in[11];
  const float* fc1_b   = (const float*)d_in[12];
  float* out = (float*)d_out;
  char* ws = (char*)d_ws;

  // timeline-aware layout (bytes), peak ~80.6 MB:
  unsigned short* xb1 = (unsigned short*)(ws + 0);         //  6,225,920 (dead after conv1)
  unsigned short* wb1 = (unsigned short*)(ws + 6291456);   //     34,816
  unsigned short* c1B = (unsigned short*)(ws + 8388608);   // 41,295,872 (dead after pool_t2)
  unsigned short* xb2 = (unsigned short*)(ws + 50331648);  // 10,323,968 (dead after conv2)
  unsigned short* wb2 = (unsigned short*)(ws + 62914560);  //     82,944 (dead after conv2)
  unsigned short* h2b = (unsigned short*)(ws + 67108864);  //  4,064,256 (dead after lc1)
  unsigned short* xb3 = (unsigned short*)(ws + 71303168);  //  3,097,600 (dead after lc2)
  unsigned short* xb4 = (unsigned short*)(ws + 75497472);  //    640,000 (dead after lc3)
  unsigned short* xb5 = (unsigned short*)(ws + 76546048);  //    451,584
  float* xB           = (float*)(ws + 77594624);           //    903,168 (fc input [b][k])
  float* fcp          = (float*)(ws + 78643200);           //  2,097,152 (fc1 partials)
  unsigned short* wbT = (unsigned short*)(ws + 0);         // <= 63,521,792 (lc weight chunks)

  prep_xb1<<<3040, 256, 0, stream>>>(x, xb1);
  prep_wb1<<<68, 256, 0, stream>>>(conv1_w, wb1);
  conv1_mfma<<<5041, 256, 0, stream>>>(xb1, wb1, conv1_b, c1B);
  pool_t2<<<631, 256, 0, stream>>>(c1B, xb2);
  prep_wb2<<<162, 256, 0, stream>>>(conv2_w, wb2);
  conv2_mfma<<<993, 256, 0, stream>>>(xb2, wb2, conv2_b, h2b);

  // lc1 in two weight chunks (63.5 MB each)
  prep_lcw<9><<<1513, 256, 0, stream>>>(lc1_w, wbT, 0);
  lc_mfma<9, 1, 63, 55><<<379, 256, 0, stream>>>(h2b, wbT, lc1_b, xb3, 0, 1513);
  prep_lcw<9><<<1512, 256, 0, stream>>>(lc1_w, wbT, 1513);
  lc_mfma<9, 1, 63, 55><<<378, 256, 0, stream>>>(h2b, wbT, lc1_b, xb3, 1513, 1512);

  prep_lcw<7><<<625, 256, 0, stream>>>(lc2_w, wbT, 0);
  lc_mfma<7, 2, 55, 25><<<157, 256, 0, stream>>>(xb3, wbT, lc2_b, xb4, 0, 625);

  prep_lcw<5><<<441, 256, 0, stream>>>(lc3_w, wbT, 0);
  lc_mfma<5, 1, 25, 21><<<111, 256, 0, stream>>>(xb4, wbT, lc3_b, xb5, 0, 441);

  fc_reformat2<<<882, 256, 0, stream>>>(xb5, xB);
  fc1_v5<<<dim3(512, 4), 256, 0, stream>>>(xB, fc1_w, fcp);
  fc_combine<<<512, 256, 0, stream>>>(fcp, fc1_b, out);
}

// Round 21
// 379.338 us; speedup vs baseline: 1.3147x; 1.0595x over previous
//
#include <hip/hip_runtime.h>
#include <cstddef>

typedef __attribute__((ext_vector_type(8))) short bf16x8;
typedef __attribute__((ext_vector_type(8), aligned(8))) short bf16x8a;
typedef __attribute__((ext_vector_type(4))) float f32x4;
typedef __attribute__((ext_vector_type(4))) unsigned short u16x4;
typedef __attribute__((ext_vector_type(8))) unsigned short u16x8;

__device__ inline unsigned short f2bf(float f) {
  unsigned int u = __float_as_uint(f);
  unsigned int r = (u + 0x7FFFu + ((u >> 16) & 1u)) >> 16;
  return (unsigned short)r;
}
__device__ inline float bf2f(unsigned short u) {
  return __uint_as_float((unsigned int)u << 16);
}

// ---------------- prep: x -> xb1 bf16 [ih152][iw160][b32][ic4]  AND
//                  conv1 w -> wb1 [step17][kc4][s32][8]   (merged)
__global__ __launch_bounds__(256) void prep_x1w1(const float* __restrict__ x,
                                                 const float* __restrict__ w,
                                                 unsigned short* __restrict__ xb,
                                                 unsigned short* __restrict__ wb) {
  if (blockIdx.x < 3040) {
    const int j = blockIdx.x * 256 + threadIdx.x;   // 778240 exact
    const int iw = j % 160;
    const int ih = (j / 160) % 152;
    const int b = j / (160 * 152);
    unsigned short v[4] = {0, 0, 0, 0};
    if (iw < 152) {
      #pragma unroll
      for (int ic = 0; ic < 3; ++ic)
        v[ic] = f2bf(x[(size_t)(b * 3 + ic) * 23104 + ih * 152 + iw]);
    }
    *(unsigned long long*)(xb + ((((size_t)ih * 160 + iw) * 32) + b) * 4) =
        *(unsigned long long*)v;
  } else {
    const int j = (blockIdx.x - 3040) * 256 + threadIdx.x;  // 17408 exact
    const int e = j & 7;
    const int s = (j >> 3) & 31;
    const int kcj = j >> 8;
    const int kc = kcj & 3, step = kcj >> 2;
    const int t = step * 8 + kc * 2 + (e >> 2);
    const int ics = e & 3;
    const int kh = t / 12, kwp = t - kh * 12;
    float val = 0.f;
    if (t < 132 && kwp < 11 && ics < 3)
      val = w[((s * 3 + ics) * 11 + kh) * 11 + kwp];
    wb[j] = f2bf(val);
  }
}

// ---------------- conv1 via MFMA: writes c1B bf16 [pos20164][b32][oc32].
__global__ __launch_bounds__(256, 4) void conv1_mfma(const unsigned short* __restrict__ xb,
                                                     const unsigned short* __restrict__ wb,
                                                     const float* __restrict__ bias,
                                                     unsigned short* __restrict__ outB) {
  const int lane = threadIdx.x & 63;
  const int wvi = threadIdx.x >> 6;
  const int pos = blockIdx.x * 4 + wvi;           // 20164 exact
  const int oh = pos / 142, ow = pos % 142;
  const int row = lane & 15;
  const int kc = lane >> 4;
  f32x4 a00 = {0.f, 0.f, 0.f, 0.f}, a01 = a00, a10 = a00, a11 = a00;

  #pragma unroll 2
  for (int j = 0; j < 17; ++j) {
    const int t0 = j * 8 + 2 * kc;
    int kh = t0 / 12;
    int kwp = t0 - kh * 12;
    if (t0 >= 132) { kh = 0; kwp = 0; }
    const bf16x8 wa0 = *(const bf16x8*)(wb + (((j * 4 + kc) * 32) + row) * 8);
    const bf16x8 wa1 = *(const bf16x8*)(wb + (((j * 4 + kc) * 32) + 16 + row) * 8);
    const size_t base = (((size_t)(oh + kh) * 160) + (ow + kwp)) * 128;
    const unsigned short* xp0 = xb + base + row * 4;
    bf16x8 xv0, xv1;
    ((unsigned long long*)&xv0)[0] = *(const unsigned long long*)(xp0);
    ((unsigned long long*)&xv0)[1] = *(const unsigned long long*)(xp0 + 128);
    ((unsigned long long*)&xv1)[0] = *(const unsigned long long*)(xp0 + 64);
    ((unsigned long long*)&xv1)[1] = *(const unsigned long long*)(xp0 + 192);
    a00 = __builtin_amdgcn_mfma_f32_16x16x32_bf16(wa0, xv0, a00, 0, 0, 0);
    a01 = __builtin_amdgcn_mfma_f32_16x16x32_bf16(wa0, xv1, a01, 0, 0, 0);
    a10 = __builtin_amdgcn_mfma_f32_16x16x32_bf16(wa1, xv0, a10, 0, 0, 0);
    a11 = __builtin_amdgcn_mfma_f32_16x16x32_bf16(wa1, xv1, a11, 0, 0, 0);
  }

  unsigned short* ob = outB + (size_t)pos * 1024;
  u16x4 p00, p01, p10, p11;
  #pragma unroll
  for (int r = 0; r < 4; ++r) {
    const float bv0 = bias[kc * 4 + r];
    const float bv1 = bias[16 + kc * 4 + r];
    p00[r] = f2bf(fmaxf(a00[r] + bv0, 0.f));
    p01[r] = f2bf(fmaxf(a01[r] + bv0, 0.f));
    p10[r] = f2bf(fmaxf(a10[r] + bv1, 0.f));
    p11[r] = f2bf(fmaxf(a11[r] + bv1, 0.f));
  }
  *(u16x4*)(ob + row * 32 + kc * 4) = p00;
  *(u16x4*)(ob + (row + 16) * 32 + kc * 4) = p01;
  *(u16x4*)(ob + row * 32 + 16 + kc * 4) = p10;
  *(u16x4*)(ob + (row + 16) * 32 + 16 + kc * 4) = p11;
}

// ---------------- pool_t2 (maxpool+transpose) AND prep_wb2 (merged).
// pool: c1B [pos][b32][oc32] -> xb2 [pos'5041][b32][ic32]; wb2: [sp81][oc16][ic32].
__global__ __launch_bounds__(256) void poolt2_wb2(const unsigned short* __restrict__ in,
                                                  unsigned short* __restrict__ xb,
                                                  const float* __restrict__ w2,
                                                  unsigned short* __restrict__ wb2) {
  if (blockIdx.x < 631) {
    const int tid = threadIdx.x;
    const int b = tid & 31, pg = tid >> 5;
    const int posp = blockIdx.x * 8 + pg;
    if (posp >= 5041) return;
    const int ohp = posp / 71, owp = posp % 71;
    u16x8 m[4];
    #pragma unroll
    for (int q = 0; q < 4; ++q)
      #pragma unroll
      for (int e = 0; e < 8; ++e) m[q][e] = 0;

    #pragma unroll
    for (int kh = 0; kh < 3; ++kh) {
      const int ih = ohp * 2 - 1 + kh;
      if (ih < 0 || ih >= 142) continue;
      #pragma unroll
      for (int kw = 0; kw < 3; ++kw) {
        const int iw = owp * 2 - 1 + kw;
        if (iw < 0 || iw >= 142) continue;
        const u16x8* p =
            (const u16x8*)(in + (((size_t)(ih * 142 + iw)) * 32 + b) * 32);
        #pragma unroll
        for (int q = 0; q < 4; ++q) {
          const u16x8 v = p[q];
          #pragma unroll
          for (int e = 0; e < 8; ++e) m[q][e] = (v[e] > m[q][e]) ? v[e] : m[q][e];
        }
      }
    }
    u16x8* o = (u16x8*)(xb + ((size_t)posp * 32 + b) * 32);
    #pragma unroll
    for (int q = 0; q < 4; ++q) o[q] = m[q];
  } else {
    const int j = (blockIdx.x - 631) * 256 + threadIdx.x;   // 41472 exact
    const int ic = j & 31, oc = (j >> 5) & 15, sp = j >> 9;
    wb2[j] = f2bf(w2[(size_t)oc * 2592 + ic * 81 + sp]);
  }
}

// ---------------- conv2 via MFMA, 4-stage grouped loads; h2b bf16 [pos][b32][oc16]
__global__ __launch_bounds__(256) void conv2_mfma(const unsigned short* __restrict__ xb,
                                                  const unsigned short* __restrict__ wb,
                                                  const float* __restrict__ bias,
                                                  unsigned short* __restrict__ outB) {
  const int lane = threadIdx.x & 63;
  const int wvi = threadIdx.x >> 6;
  int pos = blockIdx.x * 4 + wvi;
  if (pos > 3968) pos = 3968;
  const int oh = pos / 63, ow = pos % 63;
  const int row = lane & 15;
  const int kc = lane >> 4;
  f32x4 acc0 = {0.f, 0.f, 0.f, 0.f}, acc1 = {0.f, 0.f, 0.f, 0.f};
  const unsigned short* xbase = xb + (size_t)(oh * 71 + ow) * 1024;
  const int aoff = row * 32 + kc * 8;
  const int boff0 = aoff;
  const int boff1 = (row + 16) * 32 + kc * 8;

  #pragma unroll
  for (int g = 0; g < 20; ++g) {
    bf16x8 A[4], Ba[4], Bb[4];
    #pragma unroll
    for (int i = 0; i < 4; ++i) {
      const int sp = g * 4 + i;
      const int kh = sp / 9, kw = sp - kh * 9;
      A[i] = *(const bf16x8*)(wb + sp * 512 + aoff);
      const unsigned short* xp = xbase + (kh * 71 + kw) * 1024;
      Ba[i] = *(const bf16x8*)(xp + boff0);
      Bb[i] = *(const bf16x8*)(xp + boff1);
    }
    #pragma unroll
    for (int i = 0; i < 4; ++i) {
      acc0 = __builtin_amdgcn_mfma_f32_16x16x32_bf16(A[i], Ba[i], acc0, 0, 0, 0);
      acc1 = __builtin_amdgcn_mfma_f32_16x16x32_bf16(A[i], Bb[i], acc1, 0, 0, 0);
    }
  }
  {  // tail sp = 80 (kh=8, kw=8)
    const bf16x8 a = *(const bf16x8*)(wb + 80 * 512 + aoff);
    const unsigned short* xp = xbase + (8 * 71 + 8) * 1024;
    const bf16x8 b0 = *(const bf16x8*)(xp + boff0);
    const bf16x8 b1 = *(const bf16x8*)(xp + boff1);
    acc0 = __builtin_amdgcn_mfma_f32_16x16x32_bf16(a, b0, acc0, 0, 0, 0);
    acc1 = __builtin_amdgcn_mfma_f32_16x16x32_bf16(a, b1, acc1, 0, 0, 0);
  }

  u16x4 pk0, pk1;
  #pragma unroll
  for (int r = 0; r < 4; ++r) {
    const float bv = bias[kc * 4 + r];
    pk0[r] = f2bf(fmaxf(acc0[r] + bv, 0.f));
    pk1[r] = f2bf(fmaxf(acc1[r] + bv, 0.f));
  }
  *(u16x4*)(outB + (size_t)pos * 512 + row * 16 + kc * 4) = pk0;
  *(u16x4*)(outB + (size_t)pos * 512 + (row + 16) * 16 + kc * 4) = pk1;
}

// ---------------- prep all lc weights (runtime KHW), one launch.
// w [pos][oc16][ic16][KHW] f32 -> wbT bf16 [pos][pair][oc16][tl2*ic16].
__global__ __launch_bounds__(256) void prep_lcw_all(const float* __restrict__ w1,
                                                    unsigned short* __restrict__ o1,
                                                    const float* __restrict__ w2,
                                                    unsigned short* __restrict__ o2,
                                                    const float* __restrict__ w3,
                                                    unsigned short* __restrict__ o3) {
  __shared__ float ls[8 * 16 * 81];
  int blk = blockIdx.x;
  const float* wp;
  unsigned short* ob;
  int KHW;
  if (blk < 3025) {
    KHW = 81; wp = w1 + (size_t)blk * 256 * 81; ob = o1 + (size_t)blk * 41 * 512;
  } else if (blk < 3650) {
    blk -= 3025;
    KHW = 49; wp = w2 + (size_t)blk * 256 * 49; ob = o2 + (size_t)blk * 25 * 512;
  } else {
    blk -= 3650;
    KHW = 25; wp = w3 + (size_t)blk * 256 * 25; ob = o3 + (size_t)blk * 13 * 512;
  }
  const int P = (KHW + 1) / 2;
  const int tid = threadIdx.x;

  for (int half = 0; half < 2; ++half) {
    __syncthreads();
    for (int j = tid; j < 8 * 16 * KHW; j += 256)
      ls[j] = wp[half * (8 * 16 * KHW) + j];
    __syncthreads();
    for (int j = tid; j < P * 256; j += 256) {
      const int ic = j & 15, tl = (j >> 4) & 1, oc8 = (j >> 5) & 7, pair = j >> 8;
      const int tap = pair * 2 + tl;
      const float v = (tap < KHW) ? ls[(oc8 * 16 + ic) * KHW + tap] : 0.f;
      ob[(size_t)pair * 512 + (half * 8 + oc8) * 32 + tl * 16 + ic] = f2bf(v);
    }
  }
}

// ---------------- lc via MFMA, 4-stage grouped loads. wave = 1 pos.
template <int KH, int S, int IH, int OH>
__global__ __launch_bounds__(256) void lc_mfma(const unsigned short* __restrict__ xb,
                                               const unsigned short* __restrict__ wbT,
                                               const float* __restrict__ bias,
                                               unsigned short* __restrict__ out,
                                               int pos_count) {
  constexpr int KHW = KH * KH;
  constexpr int P = (KHW + 1) / 2;                 // 41/25/13, P%4 == 1
  constexpr int NPOS = OH * OH;
  const int lane = threadIdx.x & 63;
  const int wvi = threadIdx.x >> 6;
  int lpos = blockIdx.x * 4 + wvi;
  if (lpos >= pos_count) lpos = pos_count - 1;
  const int pos = lpos;
  const int oh = pos / OH, ow = pos % OH;
  const int bcol = lane & 15;
  const int kc = lane >> 4;
  const int tsel = kc >> 1;
  const int icoff = (kc & 1) * 8;
  f32x4 acc0 = {0.f, 0.f, 0.f, 0.f}, acc1 = {0.f, 0.f, 0.f, 0.f};
  const unsigned short* wp = wbT + (size_t)lpos * (P * 512) + bcol * 32 + kc * 8;
  const int xorg = (oh * S) * IH + ow * S;

  #pragma unroll
  for (int g = 0; g < P / 4; ++g) {
    bf16x8 A[4], Ba[4], Bb[4];
    #pragma unroll
    for (int i = 0; i < 4; ++i) {
      const int p = g * 4 + i;                     // p <= P-2 -> both taps valid
      const int t0 = 2 * p, t1 = 2 * p + 1;
      const int o0 = (t0 / KH) * IH + (t0 % KH);
      const int o1 = (t1 / KH) * IH + (t1 % KH);
      const int osel = tsel ? o1 : o0;
      A[i] = *(const bf16x8*)(wp + p * 512);
      const unsigned short* xp = xb + (size_t)(xorg + osel) * 512 + icoff;
      Ba[i] = *(const bf16x8*)(xp + bcol * 16);
      Bb[i] = *(const bf16x8*)(xp + (bcol + 16) * 16);
    }
    #pragma unroll
    for (int i = 0; i < 4; ++i) {
      acc0 = __builtin_amdgcn_mfma_f32_16x16x32_bf16(A[i], Ba[i], acc0, 0, 0, 0);
      acc1 = __builtin_amdgcn_mfma_f32_16x16x32_bf16(A[i], Bb[i], acc1, 0, 0, 0);
    }
  }
  {  // tail p = P-1 (pair = tap KHW-1 + zero pad)
    constexpr int p = P - 1;
    const int t0 = 2 * p;
    const int o0 = (t0 / KH) * IH + (t0 % KH);
    const bf16x8 a = *(const bf16x8*)(wp + p * 512);
    const unsigned short* xp = xb + (size_t)(xorg + o0) * 512 + icoff;
    const bf16x8 b0 = *(const bf16x8*)(xp + bcol * 16);
    const bf16x8 b1 = *(const bf16x8*)(xp + (bcol + 16) * 16);
    acc0 = __builtin_amdgcn_mfma_f32_16x16x32_bf16(a, b0, acc0, 0, 0, 0);
    acc1 = __builtin_amdgcn_mfma_f32_16x16x32_bf16(a, b1, acc1, 0, 0, 0);
  }

  u16x4 pk0, pk1;
  #pragma unroll
  for (int r = 0; r < 4; ++r) {
    const float bv = bias[(kc * 4 + r) * NPOS + pos];
    pk0[r] = f2bf(fmaxf(acc0[r] + bv, 0.f));
    pk1[r] = f2bf(fmaxf(acc1[r] + bv, 0.f));
  }
  *(u16x4*)(out + (size_t)pos * 512 + bcol * 16 + kc * 4) = pk0;
  *(u16x4*)(out + (size_t)pos * 512 + (bcol + 16) * 16 + kc * 4) = pk1;
}

// ---------------- reformat lc3 out [pos441][b32][oc16] bf16 -> xB f32 [b][k7056]
__global__ __launch_bounds__(256) void fc_reformat2(const unsigned short* __restrict__ xb5,
                                                    float* __restrict__ xB) {
  const int j = blockIdx.x * 256 + threadIdx.x;   // 225792 exact
  const int k = j % 7056;
  const int b = j / 7056;
  const int oc = k / 441, pos = k % 441;
  xB[j] = bf2f(xb5[((size_t)pos * 32 + b) * 16 + oc]);
}

// ---------------- fc1 v5: K-split x4, all loads coalesced.
__global__ __launch_bounds__(256) void fc1_v5(const float* __restrict__ xB,
                                              const float* __restrict__ w,
                                              float* __restrict__ part) {
  const int lane = threadIdx.x & 63;
  const int b0 = (threadIdx.x >> 6) * 8;
  const int n0 = blockIdx.x * 8;
  const int kch = blockIdx.y;
  const int kbase = kch * 1764;
  float acc[8][8] = {};
  for (int it = 0; it < 7; ++it) {
    const int ko = it * 256 + lane * 4;
    const int kb = kbase + ko;
    float4 wf[8], xr[8];
    if (ko < 1764) {
      #pragma unroll
      for (int n = 0; n < 8; ++n)
        wf[n] = *(const float4*)&w[(size_t)(n0 + n) * 7056 + kb];
      #pragma unroll
      for (int bb = 0; bb < 8; ++bb)
        xr[bb] = *(const float4*)&xB[(size_t)(b0 + bb) * 7056 + kb];
    } else {
      #pragma unroll
      for (int n = 0; n < 8; ++n) wf[n] = make_float4(0.f, 0.f, 0.f, 0.f);
      #pragma unroll
      for (int bb = 0; bb < 8; ++bb) xr[bb] = make_float4(0.f, 0.f, 0.f, 0.f);
    }
    #pragma unroll
    for (int n = 0; n < 8; ++n)
      #pragma unroll
      for (int bb = 0; bb < 8; ++bb) {
        acc[n][bb] += wf[n].x * xr[bb].x + wf[n].y * xr[bb].y +
                      wf[n].z * xr[bb].z + wf[n].w * xr[bb].w;
      }
  }
  #pragma unroll
  for (int n = 0; n < 8; ++n)
    #pragma unroll
    for (int c = 0; c < 8; ++c)
      #pragma unroll
      for (int m = 1; m < 64; m <<= 1)
        acc[n][c] += __shfl_xor(acc[n][c], m, 64);
  float val = 0.f;
  #pragma unroll
  for (int n = 0; n < 8; ++n)
    #pragma unroll
    for (int c = 0; c < 8; ++c)
      if (lane == n * 8 + c) val = acc[n][c];
  const int n_l = lane >> 3, b_l = lane & 7;
  part[(((size_t)kch * 4096 + n0 + n_l) * 32) + b0 + b_l] = val;
}

// combine 4 K-partials + bias -> out (32,4096)
__global__ __launch_bounds__(256) void fc_combine(const float* __restrict__ part,
                                                  const float* __restrict__ bias,
                                                  float* __restrict__ out) {
  const int j = blockIdx.x * 256 + threadIdx.x;   // 131072 exact
  const int n = j & 4095, b = j >> 12;
  float v = bias[n];
  #pragma unroll
  for (int k = 0; k < 4; ++k) v += part[(((size_t)k * 4096 + n) * 32) + b];
  out[(size_t)b * 4096 + n] = v;
}

extern "C" void kernel_launch(void* const* d_in, const int* in_sizes, int n_in,
                              void* d_out, int out_size, void* d_ws, size_t ws_size,
                              hipStream_t stream) {
  const float* x       = (const float*)d_in[0];
  const float* conv1_w = (const float*)d_in[1];
  const float* conv1_b = (const float*)d_in[2];
  const float* conv2_w = (const float*)d_in[3];
  const float* conv2_b = (const float*)d_in[4];
  const float* lc1_w   = (const float*)d_in[5];
  const float* lc1_b   = (const float*)d_in[6];
  const float* lc2_w   = (const float*)d_in[7];
  const float* lc2_b   = (const float*)d_in[8];
  const float* lc3_w   = (const float*)d_in[9];
  const float* lc3_b   = (const float*)d_in[10];
  const float* fc1_w   = (const float*)d_in[11];
  const float* fc1_b   = (const float*)d_in[12];
  float* out = (float*)d_out;
  char* ws = (char*)d_ws;

  // generous disjoint layout (~330 MB; ws is ~1 GB per harness fill size):
  unsigned short* xb1  = (unsigned short*)(ws + 0);          //  6,225,920
  unsigned short* wb1  = (unsigned short*)(ws + 8388608);    //     34,816
  unsigned short* c1B  = (unsigned short*)(ws + 16777216);   // 41,295,872
  unsigned short* xb2  = (unsigned short*)(ws + 67108864);   // 10,323,968
  unsigned short* wb2  = (unsigned short*)(ws + 83886080);   //     82,944
  unsigned short* h2b  = (unsigned short*)(ws + 92274688);   //  4,064,256
  unsigned short* xb3  = (unsigned short*)(ws + 100663296);  //  3,097,600
  unsigned short* xb4  = (unsigned short*)(ws + 109051904);  //    640,000
  unsigned short* xb5  = (unsigned short*)(ws + 117440512);  //    451,584
  float* xB            = (float*)(ws + 125829120);           //    903,168
  float* fcp           = (float*)(ws + 134217728);           //  2,097,152
  unsigned short* wbT1 = (unsigned short*)(ws + 167772160);  // 127,027,200
  unsigned short* wbT2 = (unsigned short*)(ws + 301989888);  //  16,000,000
  unsigned short* wbT3 = (unsigned short*)(ws + 318767104);  //  5,870,592

  prep_x1w1<<<3108, 256, 0, stream>>>(x, conv1_w, xb1, wb1);
  conv1_mfma<<<5041, 256, 0, stream>>>(xb1, wb1, conv1_b, c1B);
  poolt2_wb2<<<793, 256, 0, stream>>>(c1B, xb2, conv2_w, wb2);
  conv2_mfma<<<993, 256, 0, stream>>>(xb2, wb2, conv2_b, h2b);

  prep_lcw_all<<<4091, 256, 0, stream>>>(lc1_w, wbT1, lc2_w, wbT2, lc3_w, wbT3);
  lc_mfma<9, 1, 63, 55><<<757, 256, 0, stream>>>(h2b, wbT1, lc1_b, xb3, 3025);
  lc_mfma<7, 2, 55, 25><<<157, 256, 0, stream>>>(xb3, wbT2, lc2_b, xb4, 625);
  lc_mfma<5, 1, 25, 21><<<111, 256, 0, stream>>>(xb4, wbT3, lc3_b, xb5, 441);

  fc_reformat2<<<882, 256, 0, stream>>>(xb5, xB);
  fc1_v5<<<dim3(512, 4), 256, 0, stream>>>(xB, fc1_w, fcp);
  fc_combine<<<512, 256, 0, stream>>>(fcp, fc1_b, out);
}

// Round 23
// 352.521 us; speedup vs baseline: 1.4147x; 1.0761x over previous
//
#include <hip/hip_runtime.h>
#include <cstddef>

typedef __attribute__((ext_vector_type(8))) short bf16x8;
typedef __attribute__((ext_vector_type(8), aligned(8))) short bf16x8a;
typedef __attribute__((ext_vector_type(4))) float f32x4;
typedef __attribute__((ext_vector_type(4))) unsigned short u16x4;
typedef __attribute__((ext_vector_type(8))) unsigned short u16x8;

__device__ inline unsigned short f2bf(float f) {
  unsigned int u = __float_as_uint(f);
  unsigned int r = (u + 0x7FFFu + ((u >> 16) & 1u)) >> 16;
  return (unsigned short)r;
}
__device__ inline float bf2f(unsigned short u) {
  return __uint_as_float((unsigned int)u << 16);
}

// ---------------- prep: x -> xb1 bf16 [ih152][iw160][b32][ic4]  AND
//                  conv1 w -> wb1 [step17][kc4][s32][8]   (merged)
__global__ __launch_bounds__(256) void prep_x1w1(const float* __restrict__ x,
                                                 const float* __restrict__ w,
                                                 unsigned short* __restrict__ xb,
                                                 unsigned short* __restrict__ wb) {
  if (blockIdx.x < 3040) {
    const int j = blockIdx.x * 256 + threadIdx.x;   // 778240 exact
    const int iw = j % 160;
    const int ih = (j / 160) % 152;
    const int b = j / (160 * 152);
    unsigned short v[4] = {0, 0, 0, 0};
    if (iw < 152) {
      #pragma unroll
      for (int ic = 0; ic < 3; ++ic)
        v[ic] = f2bf(x[(size_t)(b * 3 + ic) * 23104 + ih * 152 + iw]);
    }
    *(unsigned long long*)(xb + ((((size_t)ih * 160 + iw) * 32) + b) * 4) =
        *(unsigned long long*)v;
  } else {
    const int j = (blockIdx.x - 3040) * 256 + threadIdx.x;  // 17408 exact
    const int e = j & 7;
    const int s = (j >> 3) & 31;
    const int kcj = j >> 8;
    const int kc = kcj & 3, step = kcj >> 2;
    const int t = step * 8 + kc * 2 + (e >> 2);
    const int ics = e & 3;
    const int kh = t / 12, kwp = t - kh * 12;
    float val = 0.f;
    if (t < 132 && kwp < 11 && ics < 3)
      val = w[((s * 3 + ics) * 11 + kh) * 11 + kwp];
    wb[j] = f2bf(val);
  }
}

// ---------------- conv1 via MFMA + LDS window sharing (19-col tile: the
// even-pair B read touches column cl+1 <= 18, which must be staged).
// Block = 4 waves, 8 consecutive ow (wave computes ow0+wvi and ow0+wvi+4).
// Writes c1B bf16 [pos20164][b32][oc32].
__global__ __launch_bounds__(256) void conv1_mfma(const unsigned short* __restrict__ xb,
                                                  const unsigned short* __restrict__ wb,
                                                  const float* __restrict__ bias,
                                                  unsigned short* __restrict__ outB) {
  __shared__ unsigned short xs[11 * 19 * 128];      // 53504 B
  const int tile = blockIdx.x;                      // 0..17
  const int oh = blockIdx.y;                        // 0..141
  const int ow0 = min(tile * 8, 134);
  const int tid = threadIdx.x;

  for (int ch = tid; ch < 3344; ch += 256) {        // 11*19*16 chunks of 16B
    const int e = ch & 15;
    const int pix = ch >> 4;
    const int c = pix % 19, r = pix / 19;           // ow0+c <= 152 (zero-padded)
    *(u16x8*)(xs + (size_t)pix * 128 + e * 8) =
        *(const u16x8*)(xb + (((size_t)(oh + r) * 160) + (ow0 + c)) * 128 + e * 8);
  }
  __syncthreads();

  const int lane = tid & 63, wvi = tid >> 6;
  const int row = lane & 15;                        // A row (oc) / B col (b)
  const int kc = lane >> 4;
  f32x4 acc[2][4];
  #pragma unroll
  for (int p = 0; p < 2; ++p)
    #pragma unroll
    for (int q = 0; q < 4; ++q) acc[p][q] = (f32x4){0.f, 0.f, 0.f, 0.f};

  #pragma unroll 2
  for (int j = 0; j < 17; ++j) {
    const int t0 = j * 8 + 2 * kc;
    int kh = t0 / 12;
    int kwp = t0 - kh * 12;
    if (t0 >= 132) { kh = 0; kwp = 0; }             // A rows are zero there
    const bf16x8 wa0 = *(const bf16x8*)(wb + (((j * 4 + kc) * 32) + row) * 8);
    const bf16x8 wa1 = *(const bf16x8*)(wb + (((j * 4 + kc) * 32) + 16 + row) * 8);
    #pragma unroll
    for (int p = 0; p < 2; ++p) {
      const int cl = wvi + p * 4 + kwp;             // <= 17; cl+1 <= 18 staged
      const unsigned short* xp = xs + (kh * 19 + cl) * 128 + row * 4;
      bf16x8 xv0, xv1;
      ((unsigned long long*)&xv0)[0] = *(const unsigned long long*)(xp);
      ((unsigned long long*)&xv0)[1] = *(const unsigned long long*)(xp + 128);
      ((unsigned long long*)&xv1)[0] = *(const unsigned long long*)(xp + 64);
      ((unsigned long long*)&xv1)[1] = *(const unsigned long long*)(xp + 192);
      acc[p][0] = __builtin_amdgcn_mfma_f32_16x16x32_bf16(wa0, xv0, acc[p][0], 0, 0, 0);
      acc[p][1] = __builtin_amdgcn_mfma_f32_16x16x32_bf16(wa0, xv1, acc[p][1], 0, 0, 0);
      acc[p][2] = __builtin_amdgcn_mfma_f32_16x16x32_bf16(wa1, xv0, acc[p][2], 0, 0, 0);
      acc[p][3] = __builtin_amdgcn_mfma_f32_16x16x32_bf16(wa1, xv1, acc[p][3], 0, 0, 0);
    }
  }

  #pragma unroll
  for (int p = 0; p < 2; ++p) {
    const int pos = oh * 142 + ow0 + wvi + p * 4;
    unsigned short* ob = outB + (size_t)pos * 1024;
    u16x4 p00, p01, p10, p11;
    #pragma unroll
    for (int r = 0; r < 4; ++r) {
      const float bv0 = bias[kc * 4 + r];
      const float bv1 = bias[16 + kc * 4 + r];
      p00[r] = f2bf(fmaxf(acc[p][0][r] + bv0, 0.f));
      p01[r] = f2bf(fmaxf(acc[p][1][r] + bv0, 0.f));
      p10[r] = f2bf(fmaxf(acc[p][2][r] + bv1, 0.f));
      p11[r] = f2bf(fmaxf(acc[p][3][r] + bv1, 0.f));
    }
    *(u16x4*)(ob + row * 32 + kc * 4) = p00;
    *(u16x4*)(ob + (row + 16) * 32 + kc * 4) = p01;
    *(u16x4*)(ob + row * 32 + 16 + kc * 4) = p10;
    *(u16x4*)(ob + (row + 16) * 32 + 16 + kc * 4) = p11;
  }
}

// ---------------- pool_t2 (maxpool+transpose) AND prep_wb2 (merged).
__global__ __launch_bounds__(256) void poolt2_wb2(const unsigned short* __restrict__ in,
                                                  unsigned short* __restrict__ xb,
                                                  const float* __restrict__ w2,
                                                  unsigned short* __restrict__ wb2) {
  if (blockIdx.x < 631) {
    const int tid = threadIdx.x;
    const int b = tid & 31, pg = tid >> 5;
    const int posp = blockIdx.x * 8 + pg;
    if (posp >= 5041) return;
    const int ohp = posp / 71, owp = posp % 71;
    u16x8 m[4];
    #pragma unroll
    for (int q = 0; q < 4; ++q)
      #pragma unroll
      for (int e = 0; e < 8; ++e) m[q][e] = 0;

    #pragma unroll
    for (int kh = 0; kh < 3; ++kh) {
      const int ih = ohp * 2 - 1 + kh;
      if (ih < 0 || ih >= 142) continue;
      #pragma unroll
      for (int kw = 0; kw < 3; ++kw) {
        const int iw = owp * 2 - 1 + kw;
        if (iw < 0 || iw >= 142) continue;
        const u16x8* p =
            (const u16x8*)(in + (((size_t)(ih * 142 + iw)) * 32 + b) * 32);
        #pragma unroll
        for (int q = 0; q < 4; ++q) {
          const u16x8 v = p[q];
          #pragma unroll
          for (int e = 0; e < 8; ++e) m[q][e] = (v[e] > m[q][e]) ? v[e] : m[q][e];
        }
      }
    }
    u16x8* o = (u16x8*)(xb + ((size_t)posp * 32 + b) * 32);
    #pragma unroll
    for (int q = 0; q < 4; ++q) o[q] = m[q];
  } else {
    const int j = (blockIdx.x - 631) * 256 + threadIdx.x;   // 41472 exact
    const int ic = j & 31, oc = (j >> 5) & 15, sp = j >> 9;
    wb2[j] = f2bf(w2[(size_t)oc * 2592 + ic * 81 + sp]);
  }
}

// ---------------- conv2 via MFMA, 4-stage grouped loads; h2b bf16 [pos][b32][oc16]
__global__ __launch_bounds__(256) void conv2_mfma(const unsigned short* __restrict__ xb,
                                                  const unsigned short* __restrict__ wb,
                                                  const float* __restrict__ bias,
                                                  unsigned short* __restrict__ outB) {
  const int lane = threadIdx.x & 63;
  const int wvi = threadIdx.x >> 6;
  int pos = blockIdx.x * 4 + wvi;
  if (pos > 3968) pos = 3968;
  const int oh = pos / 63, ow = pos % 63;
  const int row = lane & 15;
  const int kc = lane >> 4;
  f32x4 acc0 = {0.f, 0.f, 0.f, 0.f}, acc1 = {0.f, 0.f, 0.f, 0.f};
  const unsigned short* xbase = xb + (size_t)(oh * 71 + ow) * 1024;
  const int aoff = row * 32 + kc * 8;
  const int boff0 = aoff;
  const int boff1 = (row + 16) * 32 + kc * 8;

  #pragma unroll
  for (int g = 0; g < 20; ++g) {
    bf16x8 A[4], Ba[4], Bb[4];
    #pragma unroll
    for (int i = 0; i < 4; ++i) {
      const int sp = g * 4 + i;
      const int kh = sp / 9, kw = sp - kh * 9;
      A[i] = *(const bf16x8*)(wb + sp * 512 + aoff);
      const unsigned short* xp = xbase + (kh * 71 + kw) * 1024;
      Ba[i] = *(const bf16x8*)(xp + boff0);
      Bb[i] = *(const bf16x8*)(xp + boff1);
    }
    #pragma unroll
    for (int i = 0; i < 4; ++i) {
      acc0 = __builtin_amdgcn_mfma_f32_16x16x32_bf16(A[i], Ba[i], acc0, 0, 0, 0);
      acc1 = __builtin_amdgcn_mfma_f32_16x16x32_bf16(A[i], Bb[i], acc1, 0, 0, 0);
    }
  }
  {  // tail sp = 80
    const bf16x8 a = *(const bf16x8*)(wb + 80 * 512 + aoff);
    const unsigned short* xp = xbase + (8 * 71 + 8) * 1024;
    const bf16x8 b0 = *(const bf16x8*)(xp + boff0);
    const bf16x8 b1 = *(const bf16x8*)(xp + boff1);
    acc0 = __builtin_amdgcn_mfma_f32_16x16x32_bf16(a, b0, acc0, 0, 0, 0);
    acc1 = __builtin_amdgcn_mfma_f32_16x16x32_bf16(a, b1, acc1, 0, 0, 0);
  }

  u16x4 pk0, pk1;
  #pragma unroll
  for (int r = 0; r < 4; ++r) {
    const float bv = bias[kc * 4 + r];
    pk0[r] = f2bf(fmaxf(acc0[r] + bv, 0.f));
    pk1[r] = f2bf(fmaxf(acc1[r] + bv, 0.f));
  }
  *(u16x4*)(outB + (size_t)pos * 512 + row * 16 + kc * 4) = pk0;
  *(u16x4*)(outB + (size_t)pos * 512 + (row + 16) * 16 + kc * 4) = pk1;
}

// ---------------- prep all lc weights (runtime KHW), one launch.
__global__ __launch_bounds__(256) void prep_lcw_all(const float* __restrict__ w1,
                                                    unsigned short* __restrict__ o1,
                                                    const float* __restrict__ w2,
                                                    unsigned short* __restrict__ o2,
                                                    const float* __restrict__ w3,
                                                    unsigned short* __restrict__ o3) {
  __shared__ float ls[8 * 16 * 81];
  int blk = blockIdx.x;
  const float* wp;
  unsigned short* ob;
  int KHW;
  if (blk < 3025) {
    KHW = 81; wp = w1 + (size_t)blk * 256 * 81; ob = o1 + (size_t)blk * 41 * 512;
  } else if (blk < 3650) {
    blk -= 3025;
    KHW = 49; wp = w2 + (size_t)blk * 256 * 49; ob = o2 + (size_t)blk * 25 * 512;
  } else {
    blk -= 3650;
    KHW = 25; wp = w3 + (size_t)blk * 256 * 25; ob = o3 + (size_t)blk * 13 * 512;
  }
  const int P = (KHW + 1) / 2;
  const int tid = threadIdx.x;

  for (int half = 0; half < 2; ++half) {
    __syncthreads();
    for (int j = tid; j < 8 * 16 * KHW; j += 256)
      ls[j] = wp[half * (8 * 16 * KHW) + j];
    __syncthreads();
    for (int j = tid; j < P * 256; j += 256) {
      const int ic = j & 15, tl = (j >> 4) & 1, oc8 = (j >> 5) & 7, pair = j >> 8;
      const int tap = pair * 2 + tl;
      const float v = (tap < KHW) ? ls[(oc8 * 16 + ic) * KHW + tap] : 0.f;
      ob[(size_t)pair * 512 + (half * 8 + oc8) * 32 + tl * 16 + ic] = f2bf(v);
    }
  }
}

// ---------------- lc via MFMA, 4-stage grouped loads. wave = 1 pos.
template <int KH, int S, int IH, int OH>
__global__ __launch_bounds__(256) void lc_mfma(const unsigned short* __restrict__ xb,
                                               const unsigned short* __restrict__ wbT,
                                               const float* __restrict__ bias,
                                               unsigned short* __restrict__ out,
                                               int pos_count) {
  constexpr int KHW = KH * KH;
  constexpr int P = (KHW + 1) / 2;                 // 41/25/13, P%4 == 1
  constexpr int NPOS = OH * OH;
  const int lane = threadIdx.x & 63;
  const int wvi = threadIdx.x >> 6;
  int lpos = blockIdx.x * 4 + wvi;
  if (lpos >= pos_count) lpos = pos_count - 1;
  const int pos = lpos;
  const int oh = pos / OH, ow = pos % OH;
  const int bcol = lane & 15;
  const int kc = lane >> 4;
  const int tsel = kc >> 1;
  const int icoff = (kc & 1) * 8;
  f32x4 acc0 = {0.f, 0.f, 0.f, 0.f}, acc1 = {0.f, 0.f, 0.f, 0.f};
  const unsigned short* wp = wbT + (size_t)lpos * (P * 512) + bcol * 32 + kc * 8;
  const int xorg = (oh * S) * IH + ow * S;

  #pragma unroll
  for (int g = 0; g < P / 4; ++g) {
    bf16x8 A[4], Ba[4], Bb[4];
    #pragma unroll
    for (int i = 0; i < 4; ++i) {
      const int p = g * 4 + i;
      const int t0 = 2 * p, t1 = 2 * p + 1;
      const int o0 = (t0 / KH) * IH + (t0 % KH);
      const int o1 = (t1 / KH) * IH + (t1 % KH);
      const int osel = tsel ? o1 : o0;
      A[i] = *(const bf16x8*)(wp + p * 512);
      const unsigned short* xp = xb + (size_t)(xorg + osel) * 512 + icoff;
      Ba[i] = *(const bf16x8*)(xp + bcol * 16);
      Bb[i] = *(const bf16x8*)(xp + (bcol + 16) * 16);
    }
    #pragma unroll
    for (int i = 0; i < 4; ++i) {
      acc0 = __builtin_amdgcn_mfma_f32_16x16x32_bf16(A[i], Ba[i], acc0, 0, 0, 0);
      acc1 = __builtin_amdgcn_mfma_f32_16x16x32_bf16(A[i], Bb[i], acc1, 0, 0, 0);
    }
  }
  {  // tail p = P-1
    constexpr int p = P - 1;
    const int t0 = 2 * p;
    const int o0 = (t0 / KH) * IH + (t0 % KH);
    const bf16x8 a = *(const bf16x8*)(wp + p * 512);
    const unsigned short* xp = xb + (size_t)(xorg + o0) * 512 + icoff;
    const bf16x8 b0 = *(const bf16x8*)(xp + bcol * 16);
    const bf16x8 b1 = *(const bf16x8*)(xp + (bcol + 16) * 16);
    acc0 = __builtin_amdgcn_mfma_f32_16x16x32_bf16(a, b0, acc0, 0, 0, 0);
    acc1 = __builtin_amdgcn_mfma_f32_16x16x32_bf16(a, b1, acc1, 0, 0, 0);
  }

  u16x4 pk0, pk1;
  #pragma unroll
  for (int r = 0; r < 4; ++r) {
    const float bv = bias[(kc * 4 + r) * NPOS + pos];
    pk0[r] = f2bf(fmaxf(acc0[r] + bv, 0.f));
    pk1[r] = f2bf(fmaxf(acc1[r] + bv, 0.f));
  }
  *(u16x4*)(out + (size_t)pos * 512 + bcol * 16 + kc * 4) = pk0;
  *(u16x4*)(out + (size_t)pos * 512 + (bcol + 16) * 16 + kc * 4) = pk1;
}

// ---------------- reformat lc3 out [pos441][b32][oc16] bf16 -> xB f32 [b][k7056]
__global__ __launch_bounds__(256) void fc_reformat2(const unsigned short* __restrict__ xb5,
                                                    float* __restrict__ xB) {
  const int j = blockIdx.x * 256 + threadIdx.x;   // 225792 exact
  const int k = j % 7056;
  const int b = j / 7056;
  const int oc = k / 441, pos = k % 441;
  xB[j] = bf2f(xb5[((size_t)pos * 32 + b) * 16 + oc]);
}

// ---------------- fc1 v5: K-split x4, all loads coalesced.
__global__ __launch_bounds__(256) void fc1_v5(const float* __restrict__ xB,
                                              const float* __restrict__ w,
                                              float* __restrict__ part) {
  const int lane = threadIdx.x & 63;
  const int b0 = (threadIdx.x >> 6) * 8;
  const int n0 = blockIdx.x * 8;
  const int kch = blockIdx.y;
  const int kbase = kch * 1764;
  float acc[8][8] = {};
  for (int it = 0; it < 7; ++it) {
    const int ko = it * 256 + lane * 4;
    const int kb = kbase + ko;
    float4 wf[8], xr[8];
    if (ko < 1764) {
      #pragma unroll
      for (int n = 0; n < 8; ++n)
        wf[n] = *(const float4*)&w[(size_t)(n0 + n) * 7056 + kb];
      #pragma unroll
      for (int bb = 0; bb < 8; ++bb)
        xr[bb] = *(const float4*)&xB[(size_t)(b0 + bb) * 7056 + kb];
    } else {
      #pragma unroll
      for (int n = 0; n < 8; ++n) wf[n] = make_float4(0.f, 0.f, 0.f, 0.f);
      #pragma unroll
      for (int bb = 0; bb < 8; ++bb) xr[bb] = make_float4(0.f, 0.f, 0.f, 0.f);
    }
    #pragma unroll
    for (int n = 0; n < 8; ++n)
      #pragma unroll
      for (int bb = 0; bb < 8; ++bb) {
        acc[n][bb] += wf[n].x * xr[bb].x + wf[n].y * xr[bb].y +
                      wf[n].z * xr[bb].z + wf[n].w * xr[bb].w;
      }
  }
  #pragma unroll
  for (int n = 0; n < 8; ++n)
    #pragma unroll
    for (int c = 0; c < 8; ++c)
      #pragma unroll
      for (int m = 1; m < 64; m <<= 1)
        acc[n][c] += __shfl_xor(acc[n][c], m, 64);
  float val = 0.f;
  #pragma unroll
  for (int n = 0; n < 8; ++n)
    #pragma unroll
    for (int c = 0; c < 8; ++c)
      if (lane == n * 8 + c) val = acc[n][c];
  const int n_l = lane >> 3, b_l = lane & 7;
  part[(((size_t)kch * 4096 + n0 + n_l) * 32) + b0 + b_l] = val;
}

// combine 4 K-partials + bias -> out (32,4096)
__global__ __launch_bounds__(256) void fc_combine(const float* __restrict__ part,
                                                  const float* __restrict__ bias,
                                                  float* __restrict__ out) {
  const int j = blockIdx.x * 256 + threadIdx.x;   // 131072 exact
  const int n = j & 4095, b = j >> 12;
  float v = bias[n];
  #pragma unroll
  for (int k = 0; k < 4; ++k) v += part[(((size_t)k * 4096 + n) * 32) + b];
  out[(size_t)b * 4096 + n] = v;
}

extern "C" void kernel_launch(void* const* d_in, const int* in_sizes, int n_in,
                              void* d_out, int out_size, void* d_ws, size_t ws_size,
                              hipStream_t stream) {
  const float* x       = (const float*)d_in[0];
  const float* conv1_w = (const float*)d_in[1];
  const float* conv1_b = (const float*)d_in[2];
  const float* conv2_w = (const float*)d_in[3];
  const float* conv2_b = (const float*)d_in[4];
  const float* lc1_w   = (const float*)d_in[5];
  const float* lc1_b   = (const float*)d_in[6];
  const float* lc2_w   = (const float*)d_in[7];
  const float* lc2_b   = (const float*)d_in[8];
  const float* lc3_w   = (const float*)d_in[9];
  const float* lc3_b   = (const float*)d_in[10];
  const float* fc1_w   = (const float*)d_in[11];
  const float* fc1_b   = (const float*)d_in[12];
  float* out = (float*)d_out;
  char* ws = (char*)d_ws;

  // generous disjoint layout (~330 MB):
  unsigned short* xb1  = (unsigned short*)(ws + 0);          //  6,225,920
  unsigned short* wb1  = (unsigned short*)(ws + 8388608);    //     34,816
  unsigned short* c1B  = (unsigned short*)(ws + 16777216);   // 41,295,872
  unsigned short* xb2  = (unsigned short*)(ws + 67108864);   // 10,323,968
  unsigned short* wb2  = (unsigned short*)(ws + 83886080);   //     82,944
  unsigned short* h2b  = (unsigned short*)(ws + 92274688);   //  4,064,256
  unsigned short* xb3  = (unsigned short*)(ws + 100663296);  //  3,097,600
  unsigned short* xb4  = (unsigned short*)(ws + 109051904);  //    640,000
  unsigned short* xb5  = (unsigned short*)(ws + 117440512);  //    451,584
  float* xB            = (float*)(ws + 125829120);           //    903,168
  float* fcp           = (float*)(ws + 134217728);           //  2,097,152
  unsigned short* wbT1 = (unsigned short*)(ws + 167772160);  // 127,027,200
  unsigned short* wbT2 = (unsigned short*)(ws + 301989888);  //  16,000,000
  unsigned short* wbT3 = (unsigned short*)(ws + 318767104);  //  5,870,592

  prep_x1w1<<<3108, 256, 0, stream>>>(x, conv1_w, xb1, wb1);
  conv1_mfma<<<dim3(18, 142), 256, 0, stream>>>(xb1, wb1, conv1_b, c1B);
  poolt2_wb2<<<793, 256, 0, stream>>>(c1B, xb2, conv2_w, wb2);
  conv2_mfma<<<993, 256, 0, stream>>>(xb2, wb2, conv2_b, h2b);

  prep_lcw_all<<<4091, 256, 0, stream>>>(lc1_w, wbT1, lc2_w, wbT2, lc3_w, wbT3);
  lc_mfma<9, 1, 63, 55><<<757, 256, 0, stream>>>(h2b, wbT1, lc1_b, xb3, 3025);
  lc_mfma<7, 2, 55, 25><<<157, 256, 0, stream>>>(xb3, wbT2, lc2_b, xb4, 625);
  lc_mfma<5, 1, 25, 21><<<111, 256, 0, stream>>>(xb4, wbT3, lc3_b, xb5, 441);

  fc_reformat2<<<882, 256, 0, stream>>>(xb5, xB);
  fc1_v5<<<dim3(512, 4), 256, 0, stream>>>(xB, fc1_w, fcp);
  fc_combine<<<512, 256, 0, stream>>>(fcp, fc1_b, out);
}

// Round 24
// 350.220 us; speedup vs baseline: 1.4240x; 1.0066x over previous
//
#include <hip/hip_runtime.h>
#include <cstddef>

typedef __attribute__((ext_vector_type(8))) short bf16x8;
typedef __attribute__((ext_vector_type(8), aligned(8))) short bf16x8a;
typedef __attribute__((ext_vector_type(4))) float f32x4;
typedef __attribute__((ext_vector_type(4))) unsigned short u16x4;
typedef __attribute__((ext_vector_type(8))) unsigned short u16x8;

__device__ inline unsigned short f2bf(float f) {
  unsigned int u = __float_as_uint(f);
  unsigned int r = (u + 0x7FFFu + ((u >> 16) & 1u)) >> 16;
  return (unsigned short)r;
}
__device__ inline float bf2f(unsigned short u) {
  return __uint_as_float((unsigned int)u << 16);
}

// bijective XCD swizzle (m204 form): blocks bid%8==k -> contiguous band k.
__device__ inline int xcd_swz(int bid, int nwg) {
  const int xcd = bid & 7;
  const int idx = bid >> 3;
  const int q = nwg >> 3, r = nwg & 7;
  return (xcd < r) ? xcd * (q + 1) + idx : r * (q + 1) + (xcd - r) * q + idx;
}

// ---------------- prep: x -> xb1 bf16 [ih152][iw160][b32][ic4]  AND
//                  conv1 w -> wb1 [step17][kc4][s32][8]   (merged)
__global__ __launch_bounds__(256) void prep_x1w1(const float* __restrict__ x,
                                                 const float* __restrict__ w,
                                                 unsigned short* __restrict__ xb,
                                                 unsigned short* __restrict__ wb) {
  if (blockIdx.x < 3040) {
    const int j = blockIdx.x * 256 + threadIdx.x;   // 778240 exact
    const int iw = j % 160;
    const int ih = (j / 160) % 152;
    const int b = j / (160 * 152);
    unsigned short v[4] = {0, 0, 0, 0};
    if (iw < 152) {
      #pragma unroll
      for (int ic = 0; ic < 3; ++ic)
        v[ic] = f2bf(x[(size_t)(b * 3 + ic) * 23104 + ih * 152 + iw]);
    }
    *(unsigned long long*)(xb + ((((size_t)ih * 160 + iw) * 32) + b) * 4) =
        *(unsigned long long*)v;
  } else {
    const int j = (blockIdx.x - 3040) * 256 + threadIdx.x;  // 17408 exact
    const int e = j & 7;
    const int s = (j >> 3) & 31;
    const int kcj = j >> 8;
    const int kc = kcj & 3, step = kcj >> 2;
    const int t = step * 8 + kc * 2 + (e >> 2);
    const int ics = e & 3;
    const int kh = t / 12, kwp = t - kh * 12;
    float val = 0.f;
    if (t < 132 && kwp < 11 && ics < 3)
      val = w[((s * 3 + ics) * 11 + kh) * 11 + kwp];
    wb[j] = f2bf(val);
  }
}

// ---------------- conv1 via MFMA + LDS window sharing (19-col tile).
// Block = 4 waves, 8 consecutive ow (wave computes ow0+wvi and ow0+wvi+4).
// Writes c1B bf16 [pos20164][b32][oc32].
__global__ __launch_bounds__(256) void conv1_mfma(const unsigned short* __restrict__ xb,
                                                  const unsigned short* __restrict__ wb,
                                                  const float* __restrict__ bias,
                                                  unsigned short* __restrict__ outB) {
  __shared__ unsigned short xs[11 * 19 * 128];      // 53504 B
  const int tile = blockIdx.x;                      // 0..17
  const int oh = blockIdx.y;                        // 0..141
  const int ow0 = min(tile * 8, 134);
  const int tid = threadIdx.x;

  for (int ch = tid; ch < 3344; ch += 256) {        // 11*19*16 chunks of 16B
    const int e = ch & 15;
    const int pix = ch >> 4;
    const int c = pix % 19, r = pix / 19;           // ow0+c <= 152 (zero-padded)
    *(u16x8*)(xs + (size_t)pix * 128 + e * 8) =
        *(const u16x8*)(xb + (((size_t)(oh + r) * 160) + (ow0 + c)) * 128 + e * 8);
  }
  __syncthreads();

  const int lane = tid & 63, wvi = tid >> 6;
  const int row = lane & 15;                        // A row (oc) / B col (b)
  const int kc = lane >> 4;
  f32x4 acc[2][4];
  #pragma unroll
  for (int p = 0; p < 2; ++p)
    #pragma unroll
    for (int q = 0; q < 4; ++q) acc[p][q] = (f32x4){0.f, 0.f, 0.f, 0.f};

  #pragma unroll 2
  for (int j = 0; j < 17; ++j) {
    const int t0 = j * 8 + 2 * kc;
    int kh = t0 / 12;
    int kwp = t0 - kh * 12;
    if (t0 >= 132) { kh = 0; kwp = 0; }             // A rows are zero there
    const bf16x8 wa0 = *(const bf16x8*)(wb + (((j * 4 + kc) * 32) + row) * 8);
    const bf16x8 wa1 = *(const bf16x8*)(wb + (((j * 4 + kc) * 32) + 16 + row) * 8);
    #pragma unroll
    for (int p = 0; p < 2; ++p) {
      const int cl = wvi + p * 4 + kwp;             // <= 17; cl+1 <= 18 staged
      const unsigned short* xp = xs + (kh * 19 + cl) * 128 + row * 4;
      bf16x8 xv0, xv1;
      ((unsigned long long*)&xv0)[0] = *(const unsigned long long*)(xp);
      ((unsigned long long*)&xv0)[1] = *(const unsigned long long*)(xp + 128);
      ((unsigned long long*)&xv1)[0] = *(const unsigned long long*)(xp + 64);
      ((unsigned long long*)&xv1)[1] = *(const unsigned long long*)(xp + 192);
      acc[p][0] = __builtin_amdgcn_mfma_f32_16x16x32_bf16(wa0, xv0, acc[p][0], 0, 0, 0);
      acc[p][1] = __builtin_amdgcn_mfma_f32_16x16x32_bf16(wa0, xv1, acc[p][1], 0, 0, 0);
      acc[p][2] = __builtin_amdgcn_mfma_f32_16x16x32_bf16(wa1, xv0, acc[p][2], 0, 0, 0);
      acc[p][3] = __builtin_amdgcn_mfma_f32_16x16x32_bf16(wa1, xv1, acc[p][3], 0, 0, 0);
    }
  }

  #pragma unroll
  for (int p = 0; p < 2; ++p) {
    const int pos = oh * 142 + ow0 + wvi + p * 4;
    unsigned short* ob = outB + (size_t)pos * 1024;
    u16x4 p00, p01, p10, p11;
    #pragma unroll
    for (int r = 0; r < 4; ++r) {
      const float bv0 = bias[kc * 4 + r];
      const float bv1 = bias[16 + kc * 4 + r];
      p00[r] = f2bf(fmaxf(acc[p][0][r] + bv0, 0.f));
      p01[r] = f2bf(fmaxf(acc[p][1][r] + bv0, 0.f));
      p10[r] = f2bf(fmaxf(acc[p][2][r] + bv1, 0.f));
      p11[r] = f2bf(fmaxf(acc[p][3][r] + bv1, 0.f));
    }
    *(u16x4*)(ob + row * 32 + kc * 4) = p00;
    *(u16x4*)(ob + (row + 16) * 32 + kc * 4) = p01;
    *(u16x4*)(ob + row * 32 + 16 + kc * 4) = p10;
    *(u16x4*)(ob + (row + 16) * 32 + 16 + kc * 4) = p11;
  }
}

// ---------------- pool_t2 (maxpool+transpose) AND prep_wb2 (merged).
__global__ __launch_bounds__(256) void poolt2_wb2(const unsigned short* __restrict__ in,
                                                  unsigned short* __restrict__ xb,
                                                  const float* __restrict__ w2,
                                                  unsigned short* __restrict__ wb2) {
  if (blockIdx.x < 631) {
    const int tid = threadIdx.x;
    const int b = tid & 31, pg = tid >> 5;
    const int posp = blockIdx.x * 8 + pg;
    if (posp >= 5041) return;
    const int ohp = posp / 71, owp = posp % 71;
    u16x8 m[4];
    #pragma unroll
    for (int q = 0; q < 4; ++q)
      #pragma unroll
      for (int e = 0; e < 8; ++e) m[q][e] = 0;

    #pragma unroll
    for (int kh = 0; kh < 3; ++kh) {
      const int ih = ohp * 2 - 1 + kh;
      if (ih < 0 || ih >= 142) continue;
      #pragma unroll
      for (int kw = 0; kw < 3; ++kw) {
        const int iw = owp * 2 - 1 + kw;
        if (iw < 0 || iw >= 142) continue;
        const u16x8* p =
            (const u16x8*)(in + (((size_t)(ih * 142 + iw)) * 32 + b) * 32);
        #pragma unroll
        for (int q = 0; q < 4; ++q) {
          const u16x8 v = p[q];
          #pragma unroll
          for (int e = 0; e < 8; ++e) m[q][e] = (v[e] > m[q][e]) ? v[e] : m[q][e];
        }
      }
    }
    u16x8* o = (u16x8*)(xb + ((size_t)posp * 32 + b) * 32);
    #pragma unroll
    for (int q = 0; q < 4; ++q) o[q] = m[q];
  } else {
    const int j = (blockIdx.x - 631) * 256 + threadIdx.x;   // 41472 exact
    const int ic = j & 31, oc = (j >> 5) & 15, sp = j >> 9;
    wb2[j] = f2bf(w2[(size_t)oc * 2592 + ic * 81 + sp]);
  }
}

// ---------------- conv2 via MFMA, 4-stage grouped loads, XCD-band swizzle.
__global__ __launch_bounds__(256) void conv2_mfma(const unsigned short* __restrict__ xb,
                                                  const unsigned short* __restrict__ wb,
                                                  const float* __restrict__ bias,
                                                  unsigned short* __restrict__ outB) {
  const int lane = threadIdx.x & 63;
  const int wvi = threadIdx.x >> 6;
  const int bid = xcd_swz(blockIdx.x, 993);
  int pos = bid * 4 + wvi;
  if (pos > 3968) pos = 3968;
  const int oh = pos / 63, ow = pos % 63;
  const int row = lane & 15;
  const int kc = lane >> 4;
  f32x4 acc0 = {0.f, 0.f, 0.f, 0.f}, acc1 = {0.f, 0.f, 0.f, 0.f};
  const unsigned short* xbase = xb + (size_t)(oh * 71 + ow) * 1024;
  const int aoff = row * 32 + kc * 8;
  const int boff0 = aoff;
  const int boff1 = (row + 16) * 32 + kc * 8;

  #pragma unroll
  for (int g = 0; g < 20; ++g) {
    bf16x8 A[4], Ba[4], Bb[4];
    #pragma unroll
    for (int i = 0; i < 4; ++i) {
      const int sp = g * 4 + i;
      const int kh = sp / 9, kw = sp - kh * 9;
      A[i] = *(const bf16x8*)(wb + sp * 512 + aoff);
      const unsigned short* xp = xbase + (kh * 71 + kw) * 1024;
      Ba[i] = *(const bf16x8*)(xp + boff0);
      Bb[i] = *(const bf16x8*)(xp + boff1);
    }
    #pragma unroll
    for (int i = 0; i < 4; ++i) {
      acc0 = __builtin_amdgcn_mfma_f32_16x16x32_bf16(A[i], Ba[i], acc0, 0, 0, 0);
      acc1 = __builtin_amdgcn_mfma_f32_16x16x32_bf16(A[i], Bb[i], acc1, 0, 0, 0);
    }
  }
  {  // tail sp = 80
    const bf16x8 a = *(const bf16x8*)(wb + 80 * 512 + aoff);
    const unsigned short* xp = xbase + (8 * 71 + 8) * 1024;
    const bf16x8 b0 = *(const bf16x8*)(xp + boff0);
    const bf16x8 b1 = *(const bf16x8*)(xp + boff1);
    acc0 = __builtin_amdgcn_mfma_f32_16x16x32_bf16(a, b0, acc0, 0, 0, 0);
    acc1 = __builtin_amdgcn_mfma_f32_16x16x32_bf16(a, b1, acc1, 0, 0, 0);
  }

  u16x4 pk0, pk1;
  #pragma unroll
  for (int r = 0; r < 4; ++r) {
    const float bv = bias[kc * 4 + r];
    pk0[r] = f2bf(fmaxf(acc0[r] + bv, 0.f));
    pk1[r] = f2bf(fmaxf(acc1[r] + bv, 0.f));
  }
  *(u16x4*)(outB + (size_t)pos * 512 + row * 16 + kc * 4) = pk0;
  *(u16x4*)(outB + (size_t)pos * 512 + (row + 16) * 16 + kc * 4) = pk1;
}

// ---------------- prep all lc weights (runtime KHW), one launch.
__global__ __launch_bounds__(256) void prep_lcw_all(const float* __restrict__ w1,
                                                    unsigned short* __restrict__ o1,
                                                    const float* __restrict__ w2,
                                                    unsigned short* __restrict__ o2,
                                                    const float* __restrict__ w3,
                                                    unsigned short* __restrict__ o3) {
  __shared__ float ls[8 * 16 * 81];
  int blk = blockIdx.x;
  const float* wp;
  unsigned short* ob;
  int KHW;
  if (blk < 3025) {
    KHW = 81; wp = w1 + (size_t)blk * 256 * 81; ob = o1 + (size_t)blk * 41 * 512;
  } else if (blk < 3650) {
    blk -= 3025;
    KHW = 49; wp = w2 + (size_t)blk * 256 * 49; ob = o2 + (size_t)blk * 25 * 512;
  } else {
    blk -= 3650;
    KHW = 25; wp = w3 + (size_t)blk * 256 * 25; ob = o3 + (size_t)blk * 13 * 512;
  }
  const int P = (KHW + 1) / 2;
  const int tid = threadIdx.x;

  for (int half = 0; half < 2; ++half) {
    __syncthreads();
    for (int j = tid; j < 8 * 16 * KHW; j += 256)
      ls[j] = wp[half * (8 * 16 * KHW) + j];
    __syncthreads();
    for (int j = tid; j < P * 256; j += 256) {
      const int ic = j & 15, tl = (j >> 4) & 1, oc8 = (j >> 5) & 7, pair = j >> 8;
      const int tap = pair * 2 + tl;
      const float v = (tap < KHW) ? ls[(oc8 * 16 + ic) * KHW + tap] : 0.f;
      ob[(size_t)pair * 512 + (half * 8 + oc8) * 32 + tl * 16 + ic] = f2bf(v);
    }
  }
}

// ---------------- lc via MFMA, 4-stage grouped loads, XCD-band swizzle.
template <int KH, int S, int IH, int OH>
__global__ __launch_bounds__(256) void lc_mfma(const unsigned short* __restrict__ xb,
                                               const unsigned short* __restrict__ wbT,
                                               const float* __restrict__ bias,
                                               unsigned short* __restrict__ out,
                                               int pos_count) {
  constexpr int KHW = KH * KH;
  constexpr int P = (KHW + 1) / 2;                 // 41/25/13, P%4 == 1
  constexpr int NPOS = OH * OH;
  const int lane = threadIdx.x & 63;
  const int wvi = threadIdx.x >> 6;
  const int bid = xcd_swz(blockIdx.x, gridDim.x);
  int lpos = bid * 4 + wvi;
  if (lpos >= pos_count) lpos = pos_count - 1;
  const int pos = lpos;
  const int oh = pos / OH, ow = pos % OH;
  const int bcol = lane & 15;
  const int kc = lane >> 4;
  const int tsel = kc >> 1;
  const int icoff = (kc & 1) * 8;
  f32x4 acc0 = {0.f, 0.f, 0.f, 0.f}, acc1 = {0.f, 0.f, 0.f, 0.f};
  const unsigned short* wp = wbT + (size_t)lpos * (P * 512) + bcol * 32 + kc * 8;
  const int xorg = (oh * S) * IH + ow * S;

  #pragma unroll
  for (int g = 0; g < P / 4; ++g) {
    bf16x8 A[4], Ba[4], Bb[4];
    #pragma unroll
    for (int i = 0; i < 4; ++i) {
      const int p = g * 4 + i;
      const int t0 = 2 * p, t1 = 2 * p + 1;
      const int o0 = (t0 / KH) * IH + (t0 % KH);
      const int o1 = (t1 / KH) * IH + (t1 % KH);
      const int osel = tsel ? o1 : o0;
      A[i] = *(const bf16x8*)(wp + p * 512);
      const unsigned short* xp = xb + (size_t)(xorg + osel) * 512 + icoff;
      Ba[i] = *(const bf16x8*)(xp + bcol * 16);
      Bb[i] = *(const bf16x8*)(xp + (bcol + 16) * 16);
    }
    #pragma unroll
    for (int i = 0; i < 4; ++i) {
      acc0 = __builtin_amdgcn_mfma_f32_16x16x32_bf16(A[i], Ba[i], acc0, 0, 0, 0);
      acc1 = __builtin_amdgcn_mfma_f32_16x16x32_bf16(A[i], Bb[i], acc1, 0, 0, 0);
    }
  }
  {  // tail p = P-1
    constexpr int p = P - 1;
    const int t0 = 2 * p;
    const int o0 = (t0 / KH) * IH + (t0 % KH);
    const bf16x8 a = *(const bf16x8*)(wp + p * 512);
    const unsigned short* xp = xb + (size_t)(xorg + o0) * 512 + icoff;
    const bf16x8 b0 = *(const bf16x8*)(xp + bcol * 16);
    const bf16x8 b1 = *(const bf16x8*)(xp + (bcol + 16) * 16);
    acc0 = __builtin_amdgcn_mfma_f32_16x16x32_bf16(a, b0, acc0, 0, 0, 0);
    acc1 = __builtin_amdgcn_mfma_f32_16x16x32_bf16(a, b1, acc1, 0, 0, 0);
  }

  u16x4 pk0, pk1;
  #pragma unroll
  for (int r = 0; r < 4; ++r) {
    const float bv = bias[(kc * 4 + r) * NPOS + pos];
    pk0[r] = f2bf(fmaxf(acc0[r] + bv, 0.f));
    pk1[r] = f2bf(fmaxf(acc1[r] + bv, 0.f));
  }
  *(u16x4*)(out + (size_t)pos * 512 + bcol * 16 + kc * 4) = pk0;
  *(u16x4*)(out + (size_t)pos * 512 + (bcol + 16) * 16 + kc * 4) = pk1;
}

// ---------------- reformat lc3 out [pos441][b32][oc16] bf16 -> xB f32 [b][k7056]
__global__ __launch_bounds__(256) void fc_reformat2(const unsigned short* __restrict__ xb5,
                                                    float* __restrict__ xB) {
  const int j = blockIdx.x * 256 + threadIdx.x;   // 225792 exact
  const int k = j % 7056;
  const int b = j / 7056;
  const int oc = k / 441, pos = k % 441;
  xB[j] = bf2f(xb5[((size_t)pos * 32 + b) * 16 + oc]);
}

// ---------------- fc1 v5: K-split x4, all loads coalesced.
__global__ __launch_bounds__(256) void fc1_v5(const float* __restrict__ xB,
                                              const float* __restrict__ w,
                                              float* __restrict__ part) {
  const int lane = threadIdx.x & 63;
  const int b0 = (threadIdx.x >> 6) * 8;
  const int n0 = blockIdx.x * 8;
  const int kch = blockIdx.y;
  const int kbase = kch * 1764;
  float acc[8][8] = {};
  for (int it = 0; it < 7; ++it) {
    const int ko = it * 256 + lane * 4;
    const int kb = kbase + ko;
    float4 wf[8], xr[8];
    if (ko < 1764) {
      #pragma unroll
      for (int n = 0; n < 8; ++n)
        wf[n] = *(const float4*)&w[(size_t)(n0 + n) * 7056 + kb];
      #pragma unroll
      for (int bb = 0; bb < 8; ++bb)
        xr[bb] = *(const float4*)&xB[(size_t)(b0 + bb) * 7056 + kb];
    } else {
      #pragma unroll
      for (int n = 0; n < 8; ++n) wf[n] = make_float4(0.f, 0.f, 0.f, 0.f);
      #pragma unroll
      for (int bb = 0; bb < 8; ++bb) xr[bb] = make_float4(0.f, 0.f, 0.f, 0.f);
    }
    #pragma unroll
    for (int n = 0; n < 8; ++n)
      #pragma unroll
      for (int bb = 0; bb < 8; ++bb) {
        acc[n][bb] += wf[n].x * xr[bb].x + wf[n].y * xr[bb].y +
                      wf[n].z * xr[bb].z + wf[n].w * xr[bb].w;
      }
  }
  #pragma unroll
  for (int n = 0; n < 8; ++n)
    #pragma unroll
    for (int c = 0; c < 8; ++c)
      #pragma unroll
      for (int m = 1; m < 64; m <<= 1)
        acc[n][c] += __shfl_xor(acc[n][c], m, 64);
  float val = 0.f;
  #pragma unroll
  for (int n = 0; n < 8; ++n)
    #pragma unroll
    for (int c = 0; c < 8; ++c)
      if (lane == n * 8 + c) val = acc[n][c];
  const int n_l = lane >> 3, b_l = lane & 7;
  part[(((size_t)kch * 4096 + n0 + n_l) * 32) + b0 + b_l] = val;
}

// combine 4 K-partials + bias -> out (32,4096)
__global__ __launch_bounds__(256) void fc_combine(const float* __restrict__ part,
                                                  const float* __restrict__ bias,
                                                  float* __restrict__ out) {
  const int j = blockIdx.x * 256 + threadIdx.x;   // 131072 exact
  const int n = j & 4095, b = j >> 12;
  float v = bias[n];
  #pragma unroll
  for (int k = 0; k < 4; ++k) v += part[(((size_t)k * 4096 + n) * 32) + b];
  out[(size_t)b * 4096 + n] = v;
}

extern "C" void kernel_launch(void* const* d_in, const int* in_sizes, int n_in,
                              void* d_out, int out_size, void* d_ws, size_t ws_size,
                              hipStream_t stream) {
  const float* x       = (const float*)d_in[0];
  const float* conv1_w = (const float*)d_in[1];
  const float* conv1_b = (const float*)d_in[2];
  const float* conv2_w = (const float*)d_in[3];
  const float* conv2_b = (const float*)d_in[4];
  const float* lc1_w   = (const float*)d_in[5];
  const float* lc1_b   = (const float*)d_in[6];
  const float* lc2_w   = (const float*)d_in[7];
  const float* lc2_b   = (const float*)d_in[8];
  const float* lc3_w   = (const float*)d_in[9];
  const float* lc3_b   = (const float*)d_in[10];
  const float* fc1_w   = (const float*)d_in[11];
  const float* fc1_b   = (const float*)d_in[12];
  float* out = (float*)d_out;
  char* ws = (char*)d_ws;

  // generous disjoint layout (~330 MB):
  unsigned short* xb1  = (unsigned short*)(ws + 0);          //  6,225,920
  unsigned short* wb1  = (unsigned short*)(ws + 8388608);    //     34,816
  unsigned short* c1B  = (unsigned short*)(ws + 16777216);   // 41,295,872
  unsigned short* xb2  = (unsigned short*)(ws + 67108864);   // 10,323,968
  unsigned short* wb2  = (unsigned short*)(ws + 83886080);   //     82,944
  unsigned short* h2b  = (unsigned short*)(ws + 92274688);   //  4,064,256
  unsigned short* xb3  = (unsigned short*)(ws + 100663296);  //  3,097,600
  unsigned short* xb4  = (unsigned short*)(ws + 109051904);  //    640,000
  unsigned short* xb5  = (unsigned short*)(ws + 117440512);  //    451,584
  float* xB            = (float*)(ws + 125829120);           //    903,168
  float* fcp           = (float*)(ws + 134217728);           //  2,097,152
  unsigned short* wbT1 = (unsigned short*)(ws + 167772160);  // 127,027,200
  unsigned short* wbT2 = (unsigned short*)(ws + 301989888);  //  16,000,000
  unsigned short* wbT3 = (unsigned short*)(ws + 318767104);  //  5,870,592

  prep_x1w1<<<3108, 256, 0, stream>>>(x, conv1_w, xb1, wb1);
  conv1_mfma<<<dim3(18, 142), 256, 0, stream>>>(xb1, wb1, conv1_b, c1B);
  poolt2_wb2<<<793, 256, 0, stream>>>(c1B, xb2, conv2_w, wb2);
  conv2_mfma<<<993, 256, 0, stream>>>(xb2, wb2, conv2_b, h2b);

  prep_lcw_all<<<4091, 256, 0, stream>>>(lc1_w, wbT1, lc2_w, wbT2, lc3_w, wbT3);
  lc_mfma<9, 1, 63, 55><<<757, 256, 0, stream>>>(h2b, wbT1, lc1_b, xb3, 3025);
  lc_mfma<7, 2, 55, 25><<<157, 256, 0, stream>>>(xb3, wbT2, lc2_b, xb4, 625);
  lc_mfma<5, 1, 25, 21><<<111, 256, 0, stream>>>(xb4, wbT3, lc3_b, xb5, 441);

  fc_reformat2<<<882, 256, 0, stream>>>(xb5, xB);
  fc1_v5<<<dim3(512, 4), 256, 0, stream>>>(xB, fc1_w, fcp);
  fc_combine<<<512, 256, 0, stream>>>(fcp, fc1_b, out);
}

// Round 25
// 346.579 us; speedup vs baseline: 1.4389x; 1.0105x over previous
//
#include <hip/hip_runtime.h>
#include <cstddef>

typedef __attribute__((ext_vector_type(8))) short bf16x8;
typedef __attribute__((ext_vector_type(8), aligned(8))) short bf16x8a;
typedef __attribute__((ext_vector_type(4))) float f32x4;
typedef __attribute__((ext_vector_type(4))) unsigned short u16x4;
typedef __attribute__((ext_vector_type(8))) unsigned short u16x8;

__device__ inline unsigned short f2bf(float f) {
  unsigned int u = __float_as_uint(f);
  unsigned int r = (u + 0x7FFFu + ((u >> 16) & 1u)) >> 16;
  return (unsigned short)r;
}
__device__ inline float bf2f(unsigned short u) {
  return __uint_as_float((unsigned int)u << 16);
}

// bijective XCD swizzle (m204 form)
__device__ inline int xcd_swz(int bid, int nwg) {
  const int xcd = bid & 7;
  const int idx = bid >> 3;
  const int q = nwg >> 3, r = nwg & 7;
  return (xcd < r) ? xcd * (q + 1) + idx : r * (q + 1) + (xcd - r) * q + idx;
}

// ---------------- prep: x -> xb1 bf16 [ih152][iw160][b32][ic4]  AND
//                  conv1 w -> wb1 [step17][kc4][s32][8]   (merged)
__global__ __launch_bounds__(256) void prep_x1w1(const float* __restrict__ x,
                                                 const float* __restrict__ w,
                                                 unsigned short* __restrict__ xb,
                                                 unsigned short* __restrict__ wb) {
  if (blockIdx.x < 3040) {
    const int j = blockIdx.x * 256 + threadIdx.x;   // 778240 exact
    const int iw = j % 160;
    const int ih = (j / 160) % 152;
    const int b = j / (160 * 152);
    unsigned short v[4] = {0, 0, 0, 0};
    if (iw < 152) {
      #pragma unroll
      for (int ic = 0; ic < 3; ++ic)
        v[ic] = f2bf(x[(size_t)(b * 3 + ic) * 23104 + ih * 152 + iw]);
    }
    *(unsigned long long*)(xb + ((((size_t)ih * 160 + iw) * 32) + b) * 4) =
        *(unsigned long long*)v;
  } else {
    const int j = (blockIdx.x - 3040) * 256 + threadIdx.x;  // 17408 exact
    const int e = j & 7;
    const int s = (j >> 3) & 31;
    const int kcj = j >> 8;
    const int kc = kcj & 3, step = kcj >> 2;
    const int t = step * 8 + kc * 2 + (e >> 2);
    const int ics = e & 3;
    const int kh = t / 12, kwp = t - kh * 12;
    float val = 0.f;
    if (t < 132 && kwp < 11 && ics < 3)
      val = w[((s * 3 + ics) * 11 + kh) * 11 + kwp];
    wb[j] = f2bf(val);
  }
}

// ---------------- FUSED: lc-weight repack (blocks 0..4090, BW-bound)  +
//                  conv1 MFMA w/ LDS window sharing (blocks 4091..6646).
// Independent work merged into one launch so the BW-bound repack overlaps
// conv1's latency/MFMA-bound phase.
__global__ __launch_bounds__(256) void lcw_conv1(
    const float* __restrict__ w1, unsigned short* __restrict__ o1,
    const float* __restrict__ w2, unsigned short* __restrict__ o2,
    const float* __restrict__ w3, unsigned short* __restrict__ o3,
    const unsigned short* __restrict__ xb, const unsigned short* __restrict__ wb,
    const float* __restrict__ bias, unsigned short* __restrict__ outB) {
  __shared__ __align__(16) unsigned char smem[53504];
  const int tid = threadIdx.x;

  if (blockIdx.x < 4091) {
    // ---- lc weight repack: w [pos][oc16][ic16][KHW] f32 ->
    //      wbT bf16 [pos][pair][oc16][tl2*ic16]
    float* ls = (float*)smem;                        // 41472 B used
    int blk = blockIdx.x;
    const float* wp;
    unsigned short* ob;
    int KHW;
    if (blk < 3025) {
      KHW = 81; wp = w1 + (size_t)blk * 256 * 81; ob = o1 + (size_t)blk * 41 * 512;
    } else if (blk < 3650) {
      blk -= 3025;
      KHW = 49; wp = w2 + (size_t)blk * 256 * 49; ob = o2 + (size_t)blk * 25 * 512;
    } else {
      blk -= 3650;
      KHW = 25; wp = w3 + (size_t)blk * 256 * 25; ob = o3 + (size_t)blk * 13 * 512;
    }
    const int P = (KHW + 1) / 2;
    for (int half = 0; half < 2; ++half) {
      __syncthreads();
      for (int j = tid; j < 8 * 16 * KHW; j += 256)
        ls[j] = wp[half * (8 * 16 * KHW) + j];
      __syncthreads();
      for (int j = tid; j < P * 256; j += 256) {
        const int ic = j & 15, tl = (j >> 4) & 1, oc8 = (j >> 5) & 7, pair = j >> 8;
        const int tap = pair * 2 + tl;
        const float v = (tap < KHW) ? ls[(oc8 * 16 + ic) * KHW + tap] : 0.f;
        ob[(size_t)pair * 512 + (half * 8 + oc8) * 32 + tl * 16 + ic] = f2bf(v);
      }
    }
    return;
  }

  // ---- conv1 via MFMA + LDS window sharing (19-col tile)
  unsigned short* xs = (unsigned short*)smem;        // 53504 B used
  const int blk = blockIdx.x - 4091;                 // 0..2555
  const int tile = blk % 18;
  const int oh = blk / 18;                           // 0..141
  const int ow0 = min(tile * 8, 134);

  for (int ch = tid; ch < 3344; ch += 256) {         // 11*19*16 chunks of 16B
    const int e = ch & 15;
    const int pix = ch >> 4;
    const int c = pix % 19, r = pix / 19;            // ow0+c <= 152 (zero-padded)
    *(u16x8*)(xs + (size_t)pix * 128 + e * 8) =
        *(const u16x8*)(xb + (((size_t)(oh + r) * 160) + (ow0 + c)) * 128 + e * 8);
  }
  __syncthreads();

  const int lane = tid & 63, wvi = tid >> 6;
  const int row = lane & 15;                         // A row (oc) / B col (b)
  const int kc = lane >> 4;
  f32x4 acc[2][4];
  #pragma unroll
  for (int p = 0; p < 2; ++p)
    #pragma unroll
    for (int q = 0; q < 4; ++q) acc[p][q] = (f32x4){0.f, 0.f, 0.f, 0.f};

  #pragma unroll 2
  for (int j = 0; j < 17; ++j) {
    const int t0 = j * 8 + 2 * kc;
    int kh = t0 / 12;
    int kwp = t0 - kh * 12;
    if (t0 >= 132) { kh = 0; kwp = 0; }              // A rows are zero there
    const bf16x8 wa0 = *(const bf16x8*)(wb + (((j * 4 + kc) * 32) + row) * 8);
    const bf16x8 wa1 = *(const bf16x8*)(wb + (((j * 4 + kc) * 32) + 16 + row) * 8);
    #pragma unroll
    for (int p = 0; p < 2; ++p) {
      const int cl = wvi + p * 4 + kwp;              // <= 17; cl+1 <= 18 staged
      const unsigned short* xp = xs + (kh * 19 + cl) * 128 + row * 4;
      bf16x8 xv0, xv1;
      ((unsigned long long*)&xv0)[0] = *(const unsigned long long*)(xp);
      ((unsigned long long*)&xv0)[1] = *(const unsigned long long*)(xp + 128);
      ((unsigned long long*)&xv1)[0] = *(const unsigned long long*)(xp + 64);
      ((unsigned long long*)&xv1)[1] = *(const unsigned long long*)(xp + 192);
      acc[p][0] = __builtin_amdgcn_mfma_f32_16x16x32_bf16(wa0, xv0, acc[p][0], 0, 0, 0);
      acc[p][1] = __builtin_amdgcn_mfma_f32_16x16x32_bf16(wa0, xv1, acc[p][1], 0, 0, 0);
      acc[p][2] = __builtin_amdgcn_mfma_f32_16x16x32_bf16(wa1, xv0, acc[p][2], 0, 0, 0);
      acc[p][3] = __builtin_amdgcn_mfma_f32_16x16x32_bf16(wa1, xv1, acc[p][3], 0, 0, 0);
    }
  }

  #pragma unroll
  for (int p = 0; p < 2; ++p) {
    const int pos = oh * 142 + ow0 + wvi + p * 4;
    unsigned short* ob = outB + (size_t)pos * 1024;
    u16x4 p00, p01, p10, p11;
    #pragma unroll
    for (int r = 0; r < 4; ++r) {
      const float bv0 = bias[kc * 4 + r];
      const float bv1 = bias[16 + kc * 4 + r];
      p00[r] = f2bf(fmaxf(acc[p][0][r] + bv0, 0.f));
      p01[r] = f2bf(fmaxf(acc[p][1][r] + bv0, 0.f));
      p10[r] = f2bf(fmaxf(acc[p][2][r] + bv1, 0.f));
      p11[r] = f2bf(fmaxf(acc[p][3][r] + bv1, 0.f));
    }
    *(u16x4*)(ob + row * 32 + kc * 4) = p00;
    *(u16x4*)(ob + (row + 16) * 32 + kc * 4) = p01;
    *(u16x4*)(ob + row * 32 + 16 + kc * 4) = p10;
    *(u16x4*)(ob + (row + 16) * 32 + 16 + kc * 4) = p11;
  }
}

// ---------------- pool_t2 (maxpool+transpose) AND prep_wb2 (merged).
__global__ __launch_bounds__(256) void poolt2_wb2(const unsigned short* __restrict__ in,
                                                  unsigned short* __restrict__ xb,
                                                  const float* __restrict__ w2,
                                                  unsigned short* __restrict__ wb2) {
  if (blockIdx.x < 631) {
    const int tid = threadIdx.x;
    const int b = tid & 31, pg = tid >> 5;
    const int posp = blockIdx.x * 8 + pg;
    if (posp >= 5041) return;
    const int ohp = posp / 71, owp = posp % 71;
    u16x8 m[4];
    #pragma unroll
    for (int q = 0; q < 4; ++q)
      #pragma unroll
      for (int e = 0; e < 8; ++e) m[q][e] = 0;

    #pragma unroll
    for (int kh = 0; kh < 3; ++kh) {
      const int ih = ohp * 2 - 1 + kh;
      if (ih < 0 || ih >= 142) continue;
      #pragma unroll
      for (int kw = 0; kw < 3; ++kw) {
        const int iw = owp * 2 - 1 + kw;
        if (iw < 0 || iw >= 142) continue;
        const u16x8* p =
            (const u16x8*)(in + (((size_t)(ih * 142 + iw)) * 32 + b) * 32);
        #pragma unroll
        for (int q = 0; q < 4; ++q) {
          const u16x8 v = p[q];
          #pragma unroll
          for (int e = 0; e < 8; ++e) m[q][e] = (v[e] > m[q][e]) ? v[e] : m[q][e];
        }
      }
    }
    u16x8* o = (u16x8*)(xb + ((size_t)posp * 32 + b) * 32);
    #pragma unroll
    for (int q = 0; q < 4; ++q) o[q] = m[q];
  } else {
    const int j = (blockIdx.x - 631) * 256 + threadIdx.x;   // 41472 exact
    const int ic = j & 31, oc = (j >> 5) & 15, sp = j >> 9;
    wb2[j] = f2bf(w2[(size_t)oc * 2592 + ic * 81 + sp]);
  }
}

// ---------------- conv2 via MFMA, 4-stage grouped loads, XCD-band swizzle.
__global__ __launch_bounds__(256) void conv2_mfma(const unsigned short* __restrict__ xb,
                                                  const unsigned short* __restrict__ wb,
                                                  const float* __restrict__ bias,
                                                  unsigned short* __restrict__ outB) {
  const int lane = threadIdx.x & 63;
  const int wvi = threadIdx.x >> 6;
  const int bid = xcd_swz(blockIdx.x, 993);
  int pos = bid * 4 + wvi;
  if (pos > 3968) pos = 3968;
  const int oh = pos / 63, ow = pos % 63;
  const int row = lane & 15;
  const int kc = lane >> 4;
  f32x4 acc0 = {0.f, 0.f, 0.f, 0.f}, acc1 = {0.f, 0.f, 0.f, 0.f};
  const unsigned short* xbase = xb + (size_t)(oh * 71 + ow) * 1024;
  const int aoff = row * 32 + kc * 8;
  const int boff0 = aoff;
  const int boff1 = (row + 16) * 32 + kc * 8;

  #pragma unroll
  for (int g = 0; g < 20; ++g) {
    bf16x8 A[4], Ba[4], Bb[4];
    #pragma unroll
    for (int i = 0; i < 4; ++i) {
      const int sp = g * 4 + i;
      const int kh = sp / 9, kw = sp - kh * 9;
      A[i] = *(const bf16x8*)(wb + sp * 512 + aoff);
      const unsigned short* xp = xbase + (kh * 71 + kw) * 1024;
      Ba[i] = *(const bf16x8*)(xp + boff0);
      Bb[i] = *(const bf16x8*)(xp + boff1);
    }
    #pragma unroll
    for (int i = 0; i < 4; ++i) {
      acc0 = __builtin_amdgcn_mfma_f32_16x16x32_bf16(A[i], Ba[i], acc0, 0, 0, 0);
      acc1 = __builtin_amdgcn_mfma_f32_16x16x32_bf16(A[i], Bb[i], acc1, 0, 0, 0);
    }
  }
  {  // tail sp = 80
    const bf16x8 a = *(const bf16x8*)(wb + 80 * 512 + aoff);
    const unsigned short* xp = xbase + (8 * 71 + 8) * 1024;
    const bf16x8 b0 = *(const bf16x8*)(xp + boff0);
    const bf16x8 b1 = *(const bf16x8*)(xp + boff1);
    acc0 = __builtin_amdgcn_mfma_f32_16x16x32_bf16(a, b0, acc0, 0, 0, 0);
    acc1 = __builtin_amdgcn_mfma_f32_16x16x32_bf16(a, b1, acc1, 0, 0, 0);
  }

  u16x4 pk0, pk1;
  #pragma unroll
  for (int r = 0; r < 4; ++r) {
    const float bv = bias[kc * 4 + r];
    pk0[r] = f2bf(fmaxf(acc0[r] + bv, 0.f));
    pk1[r] = f2bf(fmaxf(acc1[r] + bv, 0.f));
  }
  *(u16x4*)(outB + (size_t)pos * 512 + row * 16 + kc * 4) = pk0;
  *(u16x4*)(outB + (size_t)pos * 512 + (row + 16) * 16 + kc * 4) = pk1;
}

// ---------------- lc via MFMA, 4-stage grouped loads, XCD-band swizzle.
template <int KH, int S, int IH, int OH>
__global__ __launch_bounds__(256) void lc_mfma(const unsigned short* __restrict__ xb,
                                               const unsigned short* __restrict__ wbT,
                                               const float* __restrict__ bias,
                                               unsigned short* __restrict__ out,
                                               int pos_count) {
  constexpr int KHW = KH * KH;
  constexpr int P = (KHW + 1) / 2;                 // 41/25/13, P%4 == 1
  constexpr int NPOS = OH * OH;
  const int lane = threadIdx.x & 63;
  const int wvi = threadIdx.x >> 6;
  const int bid = xcd_swz(blockIdx.x, gridDim.x);
  int lpos = bid * 4 + wvi;
  if (lpos >= pos_count) lpos = pos_count - 1;
  const int pos = lpos;
  const int oh = pos / OH, ow = pos % OH;
  const int bcol = lane & 15;
  const int kc = lane >> 4;
  const int tsel = kc >> 1;
  const int icoff = (kc & 1) * 8;
  f32x4 acc0 = {0.f, 0.f, 0.f, 0.f}, acc1 = {0.f, 0.f, 0.f, 0.f};
  const unsigned short* wp = wbT + (size_t)lpos * (P * 512) + bcol * 32 + kc * 8;
  const int xorg = (oh * S) * IH + ow * S;

  #pragma unroll
  for (int g = 0; g < P / 4; ++g) {
    bf16x8 A[4], Ba[4], Bb[4];
    #pragma unroll
    for (int i = 0; i < 4; ++i) {
      const int p = g * 4 + i;
      const int t0 = 2 * p, t1 = 2 * p + 1;
      const int o0 = (t0 / KH) * IH + (t0 % KH);
      const int o1 = (t1 / KH) * IH + (t1 % KH);
      const int osel = tsel ? o1 : o0;
      A[i] = *(const bf16x8*)(wp + p * 512);
      const unsigned short* xp = xb + (size_t)(xorg + osel) * 512 + icoff;
      Ba[i] = *(const bf16x8*)(xp + bcol * 16);
      Bb[i] = *(const bf16x8*)(xp + (bcol + 16) * 16);
    }
    #pragma unroll
    for (int i = 0; i < 4; ++i) {
      acc0 = __builtin_amdgcn_mfma_f32_16x16x32_bf16(A[i], Ba[i], acc0, 0, 0, 0);
      acc1 = __builtin_amdgcn_mfma_f32_16x16x32_bf16(A[i], Bb[i], acc1, 0, 0, 0);
    }
  }
  {  // tail p = P-1
    constexpr int p = P - 1;
    const int t0 = 2 * p;
    const int o0 = (t0 / KH) * IH + (t0 % KH);
    const bf16x8 a = *(const bf16x8*)(wp + p * 512);
    const unsigned short* xp = xb + (size_t)(xorg + o0) * 512 + icoff;
    const bf16x8 b0 = *(const bf16x8*)(xp + bcol * 16);
    const bf16x8 b1 = *(const bf16x8*)(xp + (bcol + 16) * 16);
    acc0 = __builtin_amdgcn_mfma_f32_16x16x32_bf16(a, b0, acc0, 0, 0, 0);
    acc1 = __builtin_amdgcn_mfma_f32_16x16x32_bf16(a, b1, acc1, 0, 0, 0);
  }

  u16x4 pk0, pk1;
  #pragma unroll
  for (int r = 0; r < 4; ++r) {
    const float bv = bias[(kc * 4 + r) * NPOS + pos];
    pk0[r] = f2bf(fmaxf(acc0[r] + bv, 0.f));
    pk1[r] = f2bf(fmaxf(acc1[r] + bv, 0.f));
  }
  *(u16x4*)(out + (size_t)pos * 512 + bcol * 16 + kc * 4) = pk0;
  *(u16x4*)(out + (size_t)pos * 512 + (bcol + 16) * 16 + kc * 4) = pk1;
}

// ---------------- reformat lc3 out [pos441][b32][oc16] bf16 -> xB f32 [b][k7056]
__global__ __launch_bounds__(256) void fc_reformat2(const unsigned short* __restrict__ xb5,
                                                    float* __restrict__ xB) {
  const int j = blockIdx.x * 256 + threadIdx.x;   // 225792 exact
  const int k = j % 7056;
  const int b = j / 7056;
  const int oc = k / 441, pos = k % 441;
  xB[j] = bf2f(xb5[((size_t)pos * 32 + b) * 16 + oc]);
}

// ---------------- fc1 v5: K-split x4, all loads coalesced.
__global__ __launch_bounds__(256) void fc1_v5(const float* __restrict__ xB,
                                              const float* __restrict__ w,
                                              float* __restrict__ part) {
  const int lane = threadIdx.x & 63;
  const int b0 = (threadIdx.x >> 6) * 8;
  const int n0 = blockIdx.x * 8;
  const int kch = blockIdx.y;
  const int kbase = kch * 1764;
  float acc[8][8] = {};
  for (int it = 0; it < 7; ++it) {
    const int ko = it * 256 + lane * 4;
    const int kb = kbase + ko;
    float4 wf[8], xr[8];
    if (ko < 1764) {
      #pragma unroll
      for (int n = 0; n < 8; ++n)
        wf[n] = *(const float4*)&w[(size_t)(n0 + n) * 7056 + kb];
      #pragma unroll
      for (int bb = 0; bb < 8; ++bb)
        xr[bb] = *(const float4*)&xB[(size_t)(b0 + bb) * 7056 + kb];
    } else {
      #pragma unroll
      for (int n = 0; n < 8; ++n) wf[n] = make_float4(0.f, 0.f, 0.f, 0.f);
      #pragma unroll
      for (int bb = 0; bb < 8; ++bb) xr[bb] = make_float4(0.f, 0.f, 0.f, 0.f);
    }
    #pragma unroll
    for (int n = 0; n < 8; ++n)
      #pragma unroll
      for (int bb = 0; bb < 8; ++bb) {
        acc[n][bb] += wf[n].x * xr[bb].x + wf[n].y * xr[bb].y +
                      wf[n].z * xr[bb].z + wf[n].w * xr[bb].w;
      }
  }
  #pragma unroll
  for (int n = 0; n < 8; ++n)
    #pragma unroll
    for (int c = 0; c < 8; ++c)
      #pragma unroll
      for (int m = 1; m < 64; m <<= 1)
        acc[n][c] += __shfl_xor(acc[n][c], m, 64);
  float val = 0.f;
  #pragma unroll
  for (int n = 0; n < 8; ++n)
    #pragma unroll
    for (int c = 0; c < 8; ++c)
      if (lane == n * 8 + c) val = acc[n][c];
  const int n_l = lane >> 3, b_l = lane & 7;
  part[(((size_t)kch * 4096 + n0 + n_l) * 32) + b0 + b_l] = val;
}

// combine 4 K-partials + bias -> out (32,4096)
__global__ __launch_bounds__(256) void fc_combine(const float* __restrict__ part,
                                                  const float* __restrict__ bias,
                                                  float* __restrict__ out) {
  const int j = blockIdx.x * 256 + threadIdx.x;   // 131072 exact
  const int n = j & 4095, b = j >> 12;
  float v = bias[n];
  #pragma unroll
  for (int k = 0; k < 4; ++k) v += part[(((size_t)k * 4096 + n) * 32) + b];
  out[(size_t)b * 4096 + n] = v;
}

extern "C" void kernel_launch(void* const* d_in, const int* in_sizes, int n_in,
                              void* d_out, int out_size, void* d_ws, size_t ws_size,
                              hipStream_t stream) {
  const float* x       = (const float*)d_in[0];
  const float* conv1_w = (const float*)d_in[1];
  const float* conv1_b = (const float*)d_in[2];
  const float* conv2_w = (const float*)d_in[3];
  const float* conv2_b = (const float*)d_in[4];
  const float* lc1_w   = (const float*)d_in[5];
  const float* lc1_b   = (const float*)d_in[6];
  const float* lc2_w   = (const float*)d_in[7];
  const float* lc2_b   = (const float*)d_in[8];
  const float* lc3_w   = (const float*)d_in[9];
  const float* lc3_b   = (const float*)d_in[10];
  const float* fc1_w   = (const float*)d_in[11];
  const float* fc1_b   = (const float*)d_in[12];
  float* out = (float*)d_out;
  char* ws = (char*)d_ws;

  // generous disjoint layout (~330 MB):
  unsigned short* xb1  = (unsigned short*)(ws + 0);          //  6,225,920
  unsigned short* wb1  = (unsigned short*)(ws + 8388608);    //     34,816
  unsigned short* c1B  = (unsigned short*)(ws + 16777216);   // 41,295,872
  unsigned short* xb2  = (unsigned short*)(ws + 67108864);   // 10,323,968
  unsigned short* wb2  = (unsigned short*)(ws + 83886080);   //     82,944
  unsigned short* h2b  = (unsigned short*)(ws + 92274688);   //  4,064,256
  unsigned short* xb3  = (unsigned short*)(ws + 100663296);  //  3,097,600
  unsigned short* xb4  = (unsigned short*)(ws + 109051904);  //    640,000
  unsigned short* xb5  = (unsigned short*)(ws + 117440512);  //    451,584
  float* xB            = (float*)(ws + 125829120);           //    903,168
  float* fcp           = (float*)(ws + 134217728);           //  2,097,152
  unsigned short* wbT1 = (unsigned short*)(ws + 167772160);  // 127,027,200
  unsigned short* wbT2 = (unsigned short*)(ws + 301989888);  //  16,000,000
  unsigned short* wbT3 = (unsigned short*)(ws + 318767104);  //  5,870,592

  prep_x1w1<<<3108, 256, 0, stream>>>(x, conv1_w, xb1, wb1);
  lcw_conv1<<<6647, 256, 0, stream>>>(lc1_w, wbT1, lc2_w, wbT2, lc3_w, wbT3,
                                      xb1, wb1, conv1_b, c1B);
  poolt2_wb2<<<793, 256, 0, stream>>>(c1B, xb2, conv2_w, wb2);
  conv2_mfma<<<993, 256, 0, stream>>>(xb2, wb2, conv2_b, h2b);

  lc_mfma<9, 1, 63, 55><<<757, 256, 0, stream>>>(h2b, wbT1, lc1_b, xb3, 3025);
  lc_mfma<7, 2, 55, 25><<<157, 256, 0, stream>>>(xb3, wbT2, lc2_b, xb4, 625);
  lc_mfma<5, 1, 25, 21><<<111, 256, 0, stream>>>(xb4, wbT3, lc3_b, xb5, 441);

  fc_reformat2<<<882, 256, 0, stream>>>(xb5, xB);
  fc1_v5<<<dim3(512, 4), 256, 0, stream>>>(xB, fc1_w, fcp);
  fc_combine<<<512, 256, 0, stream>>>(fcp, fc1_b, out);
}

// Round 26
// 326.894 us; speedup vs baseline: 1.5256x; 1.0602x over previous
//
#include <hip/hip_runtime.h>
#include <cstddef>

typedef __attribute__((ext_vector_type(8))) short bf16x8;
typedef __attribute__((ext_vector_type(8), aligned(8))) short bf16x8a;
typedef __attribute__((ext_vector_type(4))) float f32x4;
typedef __attribute__((ext_vector_type(4))) unsigned short u16x4;
typedef __attribute__((ext_vector_type(8))) unsigned short u16x8;

__device__ inline unsigned short f2bf(float f) {
  unsigned int u = __float_as_uint(f);
  unsigned int r = (u + 0x7FFFu + ((u >> 16) & 1u)) >> 16;
  return (unsigned short)r;
}
__device__ inline float bf2f(unsigned short u) {
  return __uint_as_float((unsigned int)u << 16);
}

// bijective XCD swizzle (m204 form)
__device__ inline int xcd_swz(int bid, int nwg) {
  const int xcd = bid & 7;
  const int idx = bid >> 3;
  const int q = nwg >> 3, r = nwg & 7;
  return (xcd < r) ? xcd * (q + 1) + idx : r * (q + 1) + (xcd - r) * q + idx;
}

// ---------------- FUSED: lc-weight repack at oc-QUARTER granularity (20.7 KB LDS,
// 7 blocks/CU) [blocks 0..16363]  +  prep x->xb1 / conv1 w->wb1 [blocks 16364..19471].
__global__ __launch_bounds__(256) void lcw_prep(
    const float* __restrict__ w1, unsigned short* __restrict__ o1,
    const float* __restrict__ w2, unsigned short* __restrict__ o2,
    const float* __restrict__ w3, unsigned short* __restrict__ o3,
    const float* __restrict__ x, const float* __restrict__ w,
    unsigned short* __restrict__ xb, unsigned short* __restrict__ wb) {
  __shared__ float ls[4 * 16 * 81];                  // 20736 B
  const int tid = threadIdx.x;

  if (blockIdx.x < 16364) {
    // ---- repack quarter: w [pos][oc16][ic16][KHW] f32 ->
    //      wbT bf16 [pos][pair][oc16][tl2*ic16], this block covers oc q*4..q*4+3
    const int q = blockIdx.x & 3;
    int blk = blockIdx.x >> 2;                       // 0..4090
    const float* wp;
    unsigned short* ob;
    int KHW;
    if (blk < 3025) {
      KHW = 81; wp = w1 + (size_t)blk * 256 * 81; ob = o1 + (size_t)blk * 41 * 512;
    } else if (blk < 3650) {
      blk -= 3025;
      KHW = 49; wp = w2 + (size_t)blk * 256 * 49; ob = o2 + (size_t)blk * 25 * 512;
    } else {
      blk -= 3650;
      KHW = 25; wp = w3 + (size_t)blk * 256 * 25; ob = o3 + (size_t)blk * 13 * 512;
    }
    const int P = (KHW + 1) / 2;
    wp += (size_t)q * 64 * KHW;
    ob += q * 128;
    for (int j = tid; j < 64 * KHW; j += 256) ls[j] = wp[j];
    __syncthreads();
    for (int j = tid; j < P * 128; j += 256) {
      const int ic = j & 15, tl = (j >> 4) & 1, ocl = (j >> 5) & 3, pair = j >> 7;
      const int tap = pair * 2 + tl;
      const float v = (tap < KHW) ? ls[(ocl * 16 + ic) * KHW + tap] : 0.f;
      ob[(size_t)pair * 512 + ocl * 32 + tl * 16 + ic] = f2bf(v);
    }
    return;
  }

  const int pblk = blockIdx.x - 16364;               // 0..3107
  if (pblk < 3040) {
    const int j = pblk * 256 + tid;                  // 778240 exact
    const int iw = j % 160;
    const int ih = (j / 160) % 152;
    const int b = j / (160 * 152);
    unsigned short v[4] = {0, 0, 0, 0};
    if (iw < 152) {
      #pragma unroll
      for (int ic = 0; ic < 3; ++ic)
        v[ic] = f2bf(x[(size_t)(b * 3 + ic) * 23104 + ih * 152 + iw]);
    }
    *(unsigned long long*)(xb + ((((size_t)ih * 160 + iw) * 32) + b) * 4) =
        *(unsigned long long*)v;
  } else {
    const int j = (pblk - 3040) * 256 + tid;         // 17408 exact
    const int e = j & 7;
    const int s = (j >> 3) & 31;
    const int kcj = j >> 8;
    const int kc = kcj & 3, step = kcj >> 2;
    const int t = step * 8 + kc * 2 + (e >> 2);
    const int ics = e & 3;
    const int kh = t / 12, kwp = t - kh * 12;
    float val = 0.f;
    if (t < 132 && kwp < 11 && ics < 3)
      val = w[((s * 3 + ics) * 11 + kh) * 11 + kwp];
    wb[j] = f2bf(val);
  }
}

// ---------------- conv1 via MFMA + LDS window sharing (19-col tile).
// Block = 4 waves, 8 consecutive ow; writes c1B bf16 [pos20164][b32][oc32].
__global__ __launch_bounds__(256) void conv1_mfma(const unsigned short* __restrict__ xb,
                                                  const unsigned short* __restrict__ wb,
                                                  const float* __restrict__ bias,
                                                  unsigned short* __restrict__ outB) {
  __shared__ unsigned short xs[11 * 19 * 128];      // 53504 B
  const int tile = blockIdx.x;                      // 0..17
  const int oh = blockIdx.y;                        // 0..141
  const int ow0 = min(tile * 8, 134);
  const int tid = threadIdx.x;

  for (int ch = tid; ch < 3344; ch += 256) {        // 11*19*16 chunks of 16B
    const int e = ch & 15;
    const int pix = ch >> 4;
    const int c = pix % 19, r = pix / 19;           // ow0+c <= 152 (zero-padded)
    *(u16x8*)(xs + (size_t)pix * 128 + e * 8) =
        *(const u16x8*)(xb + (((size_t)(oh + r) * 160) + (ow0 + c)) * 128 + e * 8);
  }
  __syncthreads();

  const int lane = tid & 63, wvi = tid >> 6;
  const int row = lane & 15;                        // A row (oc) / B col (b)
  const int kc = lane >> 4;
  f32x4 acc[2][4];
  #pragma unroll
  for (int p = 0; p < 2; ++p)
    #pragma unroll
    for (int q = 0; q < 4; ++q) acc[p][q] = (f32x4){0.f, 0.f, 0.f, 0.f};

  #pragma unroll 2
  for (int j = 0; j < 17; ++j) {
    const int t0 = j * 8 + 2 * kc;
    int kh = t0 / 12;
    int kwp = t0 - kh * 12;
    if (t0 >= 132) { kh = 0; kwp = 0; }             // A rows are zero there
    const bf16x8 wa0 = *(const bf16x8*)(wb + (((j * 4 + kc) * 32) + row) * 8);
    const bf16x8 wa1 = *(const bf16x8*)(wb + (((j * 4 + kc) * 32) + 16 + row) * 8);
    #pragma unroll
    for (int p = 0; p < 2; ++p) {
      const int cl = wvi + p * 4 + kwp;             // <= 17; cl+1 <= 18 staged
      const unsigned short* xp = xs + (kh * 19 + cl) * 128 + row * 4;
      bf16x8 xv0, xv1;
      ((unsigned long long*)&xv0)[0] = *(const unsigned long long*)(xp);
      ((unsigned long long*)&xv0)[1] = *(const unsigned long long*)(xp + 128);
      ((unsigned long long*)&xv1)[0] = *(const unsigned long long*)(xp + 64);
      ((unsigned long long*)&xv1)[1] = *(const unsigned long long*)(xp + 192);
      acc[p][0] = __builtin_amdgcn_mfma_f32_16x16x32_bf16(wa0, xv0, acc[p][0], 0, 0, 0);
      acc[p][1] = __builtin_amdgcn_mfma_f32_16x16x32_bf16(wa0, xv1, acc[p][1], 0, 0, 0);
      acc[p][2] = __builtin_amdgcn_mfma_f32_16x16x32_bf16(wa1, xv0, acc[p][2], 0, 0, 0);
      acc[p][3] = __builtin_amdgcn_mfma_f32_16x16x32_bf16(wa1, xv1, acc[p][3], 0, 0, 0);
    }
  }

  #pragma unroll
  for (int p = 0; p < 2; ++p) {
    const int pos = oh * 142 + ow0 + wvi + p * 4;
    unsigned short* ob = outB + (size_t)pos * 1024;
    u16x4 p00, p01, p10, p11;
    #pragma unroll
    for (int r = 0; r < 4; ++r) {
      const float bv0 = bias[kc * 4 + r];
      const float bv1 = bias[16 + kc * 4 + r];
      p00[r] = f2bf(fmaxf(acc[p][0][r] + bv0, 0.f));
      p01[r] = f2bf(fmaxf(acc[p][1][r] + bv0, 0.f));
      p10[r] = f2bf(fmaxf(acc[p][2][r] + bv1, 0.f));
      p11[r] = f2bf(fmaxf(acc[p][3][r] + bv1, 0.f));
    }
    *(u16x4*)(ob + row * 32 + kc * 4) = p00;
    *(u16x4*)(ob + (row + 16) * 32 + kc * 4) = p01;
    *(u16x4*)(ob + row * 32 + 16 + kc * 4) = p10;
    *(u16x4*)(ob + (row + 16) * 32 + 16 + kc * 4) = p11;
  }
}

// ---------------- pool_t2 (maxpool+transpose) AND prep_wb2 (merged).
__global__ __launch_bounds__(256) void poolt2_wb2(const unsigned short* __restrict__ in,
                                                  unsigned short* __restrict__ xb,
                                                  const float* __restrict__ w2,
                                                  unsigned short* __restrict__ wb2) {
  if (blockIdx.x < 631) {
    const int tid = threadIdx.x;
    const int b = tid & 31, pg = tid >> 5;
    const int posp = blockIdx.x * 8 + pg;
    if (posp >= 5041) return;
    const int ohp = posp / 71, owp = posp % 71;
    u16x8 m[4];
    #pragma unroll
    for (int q = 0; q < 4; ++q)
      #pragma unroll
      for (int e = 0; e < 8; ++e) m[q][e] = 0;

    #pragma unroll
    for (int kh = 0; kh < 3; ++kh) {
      const int ih = ohp * 2 - 1 + kh;
      if (ih < 0 || ih >= 142) continue;
      #pragma unroll
      for (int kw = 0; kw < 3; ++kw) {
        const int iw = owp * 2 - 1 + kw;
        if (iw < 0 || iw >= 142) continue;
        const u16x8* p =
            (const u16x8*)(in + (((size_t)(ih * 142 + iw)) * 32 + b) * 32);
        #pragma unroll
        for (int q = 0; q < 4; ++q) {
          const u16x8 v = p[q];
          #pragma unroll
          for (int e = 0; e < 8; ++e) m[q][e] = (v[e] > m[q][e]) ? v[e] : m[q][e];
        }
      }
    }
    u16x8* o = (u16x8*)(xb + ((size_t)posp * 32 + b) * 32);
    #pragma unroll
    for (int q = 0; q < 4; ++q) o[q] = m[q];
  } else {
    const int j = (blockIdx.x - 631) * 256 + threadIdx.x;   // 41472 exact
    const int ic = j & 31, oc = (j >> 5) & 15, sp = j >> 9;
    wb2[j] = f2bf(w2[(size_t)oc * 2592 + ic * 81 + sp]);
  }
}

// ---------------- conv2 via MFMA, 4-stage grouped loads, XCD-band swizzle.
__global__ __launch_bounds__(256) void conv2_mfma(const unsigned short* __restrict__ xb,
                                                  const unsigned short* __restrict__ wb,
                                                  const float* __restrict__ bias,
                                                  unsigned short* __restrict__ outB) {
  const int lane = threadIdx.x & 63;
  const int wvi = threadIdx.x >> 6;
  const int bid = xcd_swz(blockIdx.x, 993);
  int pos = bid * 4 + wvi;
  if (pos > 3968) pos = 3968;
  const int oh = pos / 63, ow = pos % 63;
  const int row = lane & 15;
  const int kc = lane >> 4;
  f32x4 acc0 = {0.f, 0.f, 0.f, 0.f}, acc1 = {0.f, 0.f, 0.f, 0.f};
  const unsigned short* xbase = xb + (size_t)(oh * 71 + ow) * 1024;
  const int aoff = row * 32 + kc * 8;
  const int boff0 = aoff;
  const int boff1 = (row + 16) * 32 + kc * 8;

  #pragma unroll
  for (int g = 0; g < 20; ++g) {
    bf16x8 A[4], Ba[4], Bb[4];
    #pragma unroll
    for (int i = 0; i < 4; ++i) {
      const int sp = g * 4 + i;
      const int kh = sp / 9, kw = sp - kh * 9;
      A[i] = *(const bf16x8*)(wb + sp * 512 + aoff);
      const unsigned short* xp = xbase + (kh * 71 + kw) * 1024;
      Ba[i] = *(const bf16x8*)(xp + boff0);
      Bb[i] = *(const bf16x8*)(xp + boff1);
    }
    #pragma unroll
    for (int i = 0; i < 4; ++i) {
      acc0 = __builtin_amdgcn_mfma_f32_16x16x32_bf16(A[i], Ba[i], acc0, 0, 0, 0);
      acc1 = __builtin_amdgcn_mfma_f32_16x16x32_bf16(A[i], Bb[i], acc1, 0, 0, 0);
    }
  }
  {  // tail sp = 80
    const bf16x8 a = *(const bf16x8*)(wb + 80 * 512 + aoff);
    const unsigned short* xp = xbase + (8 * 71 + 8) * 1024;
    const bf16x8 b0 = *(const bf16x8*)(xp + boff0);
    const bf16x8 b1 = *(const bf16x8*)(xp + boff1);
    acc0 = __builtin_amdgcn_mfma_f32_16x16x32_bf16(a, b0, acc0, 0, 0, 0);
    acc1 = __builtin_amdgcn_mfma_f32_16x16x32_bf16(a, b1, acc1, 0, 0, 0);
  }

  u16x4 pk0, pk1;
  #pragma unroll
  for (int r = 0; r < 4; ++r) {
    const float bv = bias[kc * 4 + r];
    pk0[r] = f2bf(fmaxf(acc0[r] + bv, 0.f));
    pk1[r] = f2bf(fmaxf(acc1[r] + bv, 0.f));
  }
  *(u16x4*)(outB + (size_t)pos * 512 + row * 16 + kc * 4) = pk0;
  *(u16x4*)(outB + (size_t)pos * 512 + (row + 16) * 16 + kc * 4) = pk1;
}

// ---------------- lc via MFMA, 4-stage grouped loads, XCD-band swizzle.
template <int KH, int S, int IH, int OH>
__global__ __launch_bounds__(256) void lc_mfma(const unsigned short* __restrict__ xb,
                                               const unsigned short* __restrict__ wbT,
                                               const float* __restrict__ bias,
                                               unsigned short* __restrict__ out,
                                               int pos_count) {
  constexpr int KHW = KH * KH;
  constexpr int P = (KHW + 1) / 2;                 // 41/25/13, P%4 == 1
  constexpr int NPOS = OH * OH;
  const int lane = threadIdx.x & 63;
  const int wvi = threadIdx.x >> 6;
  const int bid = xcd_swz(blockIdx.x, gridDim.x);
  int lpos = bid * 4 + wvi;
  if (lpos >= pos_count) lpos = pos_count - 1;
  const int pos = lpos;
  const int oh = pos / OH, ow = pos % OH;
  const int bcol = lane & 15;
  const int kc = lane >> 4;
  const int tsel = kc >> 1;
  const int icoff = (kc & 1) * 8;
  f32x4 acc0 = {0.f, 0.f, 0.f, 0.f}, acc1 = {0.f, 0.f, 0.f, 0.f};
  const unsigned short* wp = wbT + (size_t)lpos * (P * 512) + bcol * 32 + kc * 8;
  const int xorg = (oh * S) * IH + ow * S;

  #pragma unroll
  for (int g = 0; g < P / 4; ++g) {
    bf16x8 A[4], Ba[4], Bb[4];
    #pragma unroll
    for (int i = 0; i < 4; ++i) {
      const int p = g * 4 + i;
      const int t0 = 2 * p, t1 = 2 * p + 1;
      const int o0 = (t0 / KH) * IH + (t0 % KH);
      const int o1 = (t1 / KH) * IH + (t1 % KH);
      const int osel = tsel ? o1 : o0;
      A[i] = *(const bf16x8*)(wp + p * 512);
      const unsigned short* xp = xb + (size_t)(xorg + osel) * 512 + icoff;
      Ba[i] = *(const bf16x8*)(xp + bcol * 16);
      Bb[i] = *(const bf16x8*)(xp + (bcol + 16) * 16);
    }
    #pragma unroll
    for (int i = 0; i < 4; ++i) {
      acc0 = __builtin_amdgcn_mfma_f32_16x16x32_bf16(A[i], Ba[i], acc0, 0, 0, 0);
      acc1 = __builtin_amdgcn_mfma_f32_16x16x32_bf16(A[i], Bb[i], acc1, 0, 0, 0);
    }
  }
  {  // tail p = P-1
    constexpr int p = P - 1;
    const int t0 = 2 * p;
    const int o0 = (t0 / KH) * IH + (t0 % KH);
    const bf16x8 a = *(const bf16x8*)(wp + p * 512);
    const unsigned short* xp = xb + (size_t)(xorg + o0) * 512 + icoff;
    const bf16x8 b0 = *(const bf16x8*)(xp + bcol * 16);
    const bf16x8 b1 = *(const bf16x8*)(xp + (bcol + 16) * 16);
    acc0 = __builtin_amdgcn_mfma_f32_16x16x32_bf16(a, b0, acc0, 0, 0, 0);
    acc1 = __builtin_amdgcn_mfma_f32_16x16x32_bf16(a, b1, acc1, 0, 0, 0);
  }

  u16x4 pk0, pk1;
  #pragma unroll
  for (int r = 0; r < 4; ++r) {
    const float bv = bias[(kc * 4 + r) * NPOS + pos];
    pk0[r] = f2bf(fmaxf(acc0[r] + bv, 0.f));
    pk1[r] = f2bf(fmaxf(acc1[r] + bv, 0.f));
  }
  *(u16x4*)(out + (size_t)pos * 512 + bcol * 16 + kc * 4) = pk0;
  *(u16x4*)(out + (size_t)pos * 512 + (bcol + 16) * 16 + kc * 4) = pk1;
}

// ---------------- reformat lc3 out [pos441][b32][oc16] bf16 -> xB f32 [b][k7056]
__global__ __launch_bounds__(256) void fc_reformat2(const unsigned short* __restrict__ xb5,
                                                    float* __restrict__ xB) {
  const int j = blockIdx.x * 256 + threadIdx.x;   // 225792 exact
  const int k = j % 7056;
  const int b = j / 7056;
  const int oc = k / 441, pos = k % 441;
  xB[j] = bf2f(xb5[((size_t)pos * 32 + b) * 16 + oc]);
}

// ---------------- fc1 v5: K-split x4, all loads coalesced.
__global__ __launch_bounds__(256) void fc1_v5(const float* __restrict__ xB,
                                              const float* __restrict__ w,
                                              float* __restrict__ part) {
  const int lane = threadIdx.x & 63;
  const int b0 = (threadIdx.x >> 6) * 8;
  const int n0 = blockIdx.x * 8;
  const int kch = blockIdx.y;
  const int kbase = kch * 1764;
  float acc[8][8] = {};
  for (int it = 0; it < 7; ++it) {
    const int ko = it * 256 + lane * 4;
    const int kb = kbase + ko;
    float4 wf[8], xr[8];
    if (ko < 1764) {
      #pragma unroll
      for (int n = 0; n < 8; ++n)
        wf[n] = *(const float4*)&w[(size_t)(n0 + n) * 7056 + kb];
      #pragma unroll
      for (int bb = 0; bb < 8; ++bb)
        xr[bb] = *(const float4*)&xB[(size_t)(b0 + bb) * 7056 + kb];
    } else {
      #pragma unroll
      for (int n = 0; n < 8; ++n) wf[n] = make_float4(0.f, 0.f, 0.f, 0.f);
      #pragma unroll
      for (int bb = 0; bb < 8; ++bb) xr[bb] = make_float4(0.f, 0.f, 0.f, 0.f);
    }
    #pragma unroll
    for (int n = 0; n < 8; ++n)
      #pragma unroll
      for (int bb = 0; bb < 8; ++bb) {
        acc[n][bb] += wf[n].x * xr[bb].x + wf[n].y * xr[bb].y +
                      wf[n].z * xr[bb].z + wf[n].w * xr[bb].w;
      }
  }
  #pragma unroll
  for (int n = 0; n < 8; ++n)
    #pragma unroll
    for (int c = 0; c < 8; ++c)
      #pragma unroll
      for (int m = 1; m < 64; m <<= 1)
        acc[n][c] += __shfl_xor(acc[n][c], m, 64);
  float val = 0.f;
  #pragma unroll
  for (int n = 0; n < 8; ++n)
    #pragma unroll
    for (int c = 0; c < 8; ++c)
      if (lane == n * 8 + c) val = acc[n][c];
  const int n_l = lane >> 3, b_l = lane & 7;
  part[(((size_t)kch * 4096 + n0 + n_l) * 32) + b0 + b_l] = val;
}

// combine 4 K-partials + bias -> out (32,4096)
__global__ __launch_bounds__(256) void fc_combine(const float* __restrict__ part,
                                                  const float* __restrict__ bias,
                                                  float* __restrict__ out) {
  const int j = blockIdx.x * 256 + threadIdx.x;   // 131072 exact
  const int n = j & 4095, b = j >> 12;
  float v = bias[n];
  #pragma unroll
  for (int k = 0; k < 4; ++k) v += part[(((size_t)k * 4096 + n) * 32) + b];
  out[(size_t)b * 4096 + n] = v;
}

extern "C" void kernel_launch(void* const* d_in, const int* in_sizes, int n_in,
                              void* d_out, int out_size, void* d_ws, size_t ws_size,
                              hipStream_t stream) {
  const float* x       = (const float*)d_in[0];
  const float* conv1_w = (const float*)d_in[1];
  const float* conv1_b = (const float*)d_in[2];
  const float* conv2_w = (const float*)d_in[3];
  const float* conv2_b = (const float*)d_in[4];
  const float* lc1_w   = (const float*)d_in[5];
  const float* lc1_b   = (const float*)d_in[6];
  const float* lc2_w   = (const float*)d_in[7];
  const float* lc2_b   = (const float*)d_in[8];
  const float* lc3_w   = (const float*)d_in[9];
  const float* lc3_b   = (const float*)d_in[10];
  const float* fc1_w   = (const float*)d_in[11];
  const float* fc1_b   = (const float*)d_in[12];
  float* out = (float*)d_out;
  char* ws = (char*)d_ws;

  // generous disjoint layout (~330 MB):
  unsigned short* xb1  = (unsigned short*)(ws + 0);          //  6,225,920
  unsigned short* wb1  = (unsigned short*)(ws + 8388608);    //     34,816
  unsigned short* c1B  = (unsigned short*)(ws + 16777216);   // 41,295,872
  unsigned short* xb2  = (unsigned short*)(ws + 67108864);   // 10,323,968
  unsigned short* wb2  = (unsigned short*)(ws + 83886080);   //     82,944
  unsigned short* h2b  = (unsigned short*)(ws + 92274688);   //  4,064,256
  unsigned short* xb3  = (unsigned short*)(ws + 100663296);  //  3,097,600
  unsigned short* xb4  = (unsigned short*)(ws + 109051904);  //    640,000
  unsigned short* xb5  = (unsigned short*)(ws + 117440512);  //    451,584
  float* xB            = (float*)(ws + 125829120);           //    903,168
  float* fcp           = (float*)(ws + 134217728);           //  2,097,152
  unsigned short* wbT1 = (unsigned short*)(ws + 167772160);  // 127,027,200
  unsigned short* wbT2 = (unsigned short*)(ws + 301989888);  //  16,000,000
  unsigned short* wbT3 = (unsigned short*)(ws + 318767104);  //  5,870,592

  lcw_prep<<<19472, 256, 0, stream>>>(lc1_w, wbT1, lc2_w, wbT2, lc3_w, wbT3,
                                      x, conv1_w, xb1, wb1);
  conv1_mfma<<<dim3(18, 142), 256, 0, stream>>>(xb1, wb1, conv1_b, c1B);
  poolt2_wb2<<<793, 256, 0, stream>>>(c1B, xb2, conv2_w, wb2);
  conv2_mfma<<<993, 256, 0, stream>>>(xb2, wb2, conv2_b, h2b);

  lc_mfma<9, 1, 63, 55><<<757, 256, 0, stream>>>(h2b, wbT1, lc1_b, xb3, 3025);
  lc_mfma<7, 2, 55, 25><<<313, 256, 0, stream>>>(xb3, wbT2, lc2_b, xb4, 625);
  lc_mfma<5, 1, 25, 21><<<111, 256, 0, stream>>>(xb4, wbT3, lc3_b, xb5, 441);

  fc_reformat2<<<882, 256, 0, stream>>>(xb5, xB);
  fc1_v5<<<dim3(512, 4), 256, 0, stream>>>(xB, fc1_w, fcp);
  fc_combine<<<512, 256, 0, stream>>>(fcp, fc1_b, out);
}